// Round 7
// baseline (332.675 us; speedup 1.0000x reference)
//
#include <hip/hip_runtime.h>
#include <math.h>

// Problem constants
#define Bn 4
#define Cn 64
#define Np 4096   // 64*64
#define NSPLIT 2
// SCALE * log2(e): folded into all Q pre-scales; attention uses exp2f (native v_exp_f32)
#define SCALE2 0.18033688011112042f

typedef unsigned short ushort_t;
typedef __attribute__((ext_vector_type(4))) float f32x4;
typedef __attribute__((ext_vector_type(8))) short bf16x8;

__device__ __forceinline__ float gelu_exact(float x) {
    return 0.5f * x * (1.0f + erff(x * 0.70710678118654752440f));
}
__device__ __forceinline__ ushort_t f2bf(float f) {       // RNE float->bf16
    unsigned int u = __float_as_uint(f);
    u += 0x7fffu + ((u >> 16) & 1u);
    return (ushort_t)(u >> 16);
}
__device__ __forceinline__ void gload_lds16(const ushort_t* g, ushort_t* l) {
    __builtin_amdgcn_global_load_lds(
        (const __attribute__((address_space(1))) void*)g,
        (__attribute__((address_space(3))) void*)l, 16, 0, 0);
}
__device__ __forceinline__ bf16x8 cvt8(const float v[8]) {
    bf16x8 r;
    #pragma unroll
    for (int j = 0; j < 8; ++j) r[j] = (short)f2bf(v[j]);
    return r;
}
// Normal orientation: D[n][o] — A = x rows, B = W rows. acc C-layout: row=n, col=o.
__device__ __forceinline__ void gemm16(const bf16x8 af[2], const float* __restrict__ W,
                                       int l16, int quad, f32x4* acc) {
    #pragma unroll
    for (int cb = 0; cb < 4; ++cb) {
        #pragma unroll
        for (int ks = 0; ks < 2; ++ks) {
            const float* p = W + (cb * 16 + l16) * 64 + ks * 32 + quad * 8;
            float v[8];
            #pragma unroll
            for (int j = 0; j < 8; ++j) v[j] = p[j];
            acc[cb] = __builtin_amdgcn_mfma_f32_16x16x32_bf16(af[ks], cvt8(v), acc[cb], 0, 0, 0);
        }
    }
}
// Transposed orientation: D[o][n] — A = W rows, B = x rows (same register layout both roles).
// acc C-layout: row(quad*4+r)=o_sub, col(l16)=n. Enables ushort4 channel-packed BNC stores.
__device__ __forceinline__ void gemm16T(const bf16x8 af[2], const float* __restrict__ W,
                                        int l16, int quad, f32x4* acc) {
    #pragma unroll
    for (int cb = 0; cb < 4; ++cb) {
        #pragma unroll
        for (int ks = 0; ks < 2; ++ks) {
            const float* p = W + (cb * 16 + l16) * 64 + ks * 32 + quad * 8;
            float v[8];
            #pragma unroll
            for (int j = 0; j < 8; ++j) v[j] = p[j];
            acc[cb] = __builtin_amdgcn_mfma_f32_16x16x32_bf16(cvt8(v), af[ks], acc[cb], 0, 0, 0);
        }
    }
}
// A-fragments (row, k=c) from xs tile stored [c][n] stride 65 (conflict-free)
__device__ __forceinline__ void aload(const float* xs, int row, int quad, bf16x8 af[2]) {
    #pragma unroll
    for (int ks = 0; ks < 2; ++ks) {
        float v[8];
        #pragma unroll
        for (int j = 0; j < 8; ++j) v[j] = xs[(ks * 32 + quad * 8 + j) * 65 + row];
        af[ks] = cvt8(v);
    }
}
__device__ __forceinline__ void stage_bchw(const float* __restrict__ X, int b, int n0, int t,
                                           float* xs) {
    #pragma unroll
    for (int u = 0; u < 16; ++u) {
        int idx = t + u * 256;
        int c = idx >> 6, nl = idx & 63;
        xs[c * 65 + nl] = X[((size_t)(b * Cn + c)) * Np + n0 + nl];
    }
}
// combine NSPLIT attention partials (BNC fp32) * 1/l  -> xs
__device__ __forceinline__ void stage_comb(const float* __restrict__ Op, const float* linv,
                                           int b, int n0, int t, float* xs) {
    const size_t SS = (size_t)Bn * Np * Cn;
    #pragma unroll
    for (int u = 0; u < 16; ++u) {
        int idx = t + u * 256;
        int nl = idx >> 6, c = idx & 63;
        size_t gi = ((size_t)(b * Np + n0 + nl)) * Cn + c;
        xs[c * 65 + nl] = (Op[gi] + Op[SS + gi]) * linv[nl];
    }
}
// Transposed-C BNC store: per cb one ushort4 of 4 consecutive channels at n=l16-row.
__device__ __forceinline__ void store_bnc_T(ushort_t* __restrict__ Y, int b, int n, int quad,
                                            const f32x4* acc, const float* __restrict__ bias,
                                            float mult) {
    #pragma unroll
    for (int cb = 0; cb < 4; ++cb) {
        int o0 = cb * 16 + quad * 4;
        ushort4 pk;
        pk.x = f2bf((acc[cb][0] + bias[o0 + 0]) * mult);
        pk.y = f2bf((acc[cb][1] + bias[o0 + 1]) * mult);
        pk.z = f2bf((acc[cb][2] + bias[o0 + 2]) * mult);
        pk.w = f2bf((acc[cb][3] + bias[o0 + 3]) * mult);
        *(ushort4*)(Y + ((size_t)(b * Np + n)) * Cn + o0) = pk;
    }
}
__device__ __forceinline__ void store_bchw_bf16(ushort_t* __restrict__ Y, int b, int nb, int l16,
                                                const f32x4* acc, const float* __restrict__ bias) {
    #pragma unroll
    for (int cb = 0; cb < 4; ++cb) {
        int col = cb * 16 + l16;
        float bb = bias[col];
        ushort4 pk;
        pk.x = f2bf(acc[cb][0] + bb); pk.y = f2bf(acc[cb][1] + bb);
        pk.z = f2bf(acc[cb][2] + bb); pk.w = f2bf(acc[cb][3] + bb);
        *(ushort4*)(Y + ((size_t)(b * Cn + col)) * Np + nb) = pk;
    }
}

// ---------------------------------------------------------------- avgpool 2x2 + per-block GAP partials
// blocks [0,4096): avgpool; blocks [4096,4128): wcomb (merged to save a dispatch).
__global__ void avgpool_kernel(const float* __restrict__ x, float* __restrict__ xp,
                               float* __restrict__ gap4k,
                               const float* __restrict__ convh_w, const float* __restrict__ convh_b,
                               const float* __restrict__ sch_pw, const float* __restrict__ sch_pwb,
                               const float* __restrict__ scv_pw, const float* __restrict__ scv_pwb,
                               float* __restrict__ Wc1, float* __restrict__ Wc2,
                               float* __restrict__ bcv) {
    if (blockIdx.x < 4096) {
        int idx = blockIdx.x * 256 + threadIdx.x;
        int j  = idx & 63;
        int i  = (idx >> 6) & 63;
        int bc = idx >> 12;
        const float* p = x + ((size_t)bc * 128 + 2 * i) * 128 + 2 * j;
        float v = 0.25f * (p[0] + p[1] + p[128] + p[129]);
        xp[idx] = v;
        float s = v;
        #pragma unroll
        for (int off = 1; off < 64; off <<= 1) s += __shfl_xor(s, off, 64);
        __shared__ float sm[4];
        if ((threadIdx.x & 63) == 0) sm[threadIdx.x >> 6] = s;
        __syncthreads();
        if (threadIdx.x == 0) gap4k[blockIdx.x] = sm[0] + sm[1] + sm[2] + sm[3];
    } else {
        // weight combine: Wc1 = S2*convh@sch_pw, Wc2 = S2*convh@scv_pw, bcv fused bias
        int g = (blockIdx.x - 4096) * 256 + threadIdx.x;   // 8192 threads
        int sel = g >> 12, idx = g & 4095;
        int o = idx >> 6, c = idx & 63;
        const float* pw = sel ? scv_pw : sch_pw;
        float acc = 0.f;
        #pragma unroll 8
        for (int m = 0; m < 64; ++m) acc += convh_w[o * 64 + m] * pw[m * 64 + c];
        (sel ? Wc2 : Wc1)[idx] = acc * SCALE2;
        if (g < 64) {
            float ab = convh_b[g];
            for (int m = 0; m < 64; ++m) ab += convh_w[g * 64 + m] * (sch_pwb[m] + scv_pwb[m]);
            bcv[g] = ab * SCALE2;
        }
    }
}

// ---------------------------------------------------------------- fused QKV + Wo (MFMA, 4 GEMMs)
__global__ __launch_bounds__(256) void qkv_mfma(
    const float* __restrict__ xp, const float* __restrict__ gap4k,
    const float* __restrict__ Wq, const float* __restrict__ bq,
    const float* __restrict__ Wk, const float* __restrict__ bk,
    const float* __restrict__ Wv, const float* __restrict__ bv,
    const float* __restrict__ Wo, const float* __restrict__ bo,
    ushort_t* __restrict__ qb, ushort_t* __restrict__ kb, ushort_t* __restrict__ vb,
    float* __restrict__ xV, ushort_t* __restrict__ xVtb) {
    __shared__ float xs[64 * 65];
    __shared__ float gl[64];
    int b = blockIdx.y, n0 = blockIdx.x * 64, t = threadIdx.x;
    int wv_ = t >> 6, lane = t & 63, l16 = lane & 15, quad = lane >> 4;
    stage_bchw(xp, b, n0, t, xs);
    if (t < 64) {
        float s = 0.f;
        #pragma unroll
        for (int u = 0; u < 16; ++u) s += gap4k[(b * 64 + t) * 16 + u];
        gl[t] = s * (1.f / 4096.f);
    }
    __syncthreads();
    int row = wv_ * 16 + l16;
    int n   = n0 + wv_ * 16 + l16;        // n covered in transposed C
    int nb  = n0 + wv_ * 16 + quad * 4;   // n covered in normal C
    bf16x8 ar[2], ag[2];
    #pragma unroll
    for (int ks = 0; ks < 2; ++ks) {
        float vr[8], vg[8];
        #pragma unroll
        for (int j = 0; j < 8; ++j) {
            int k = ks * 32 + quad * 8 + j;
            float xv = xs[k * 65 + row];
            vr[j] = xv; vg[j] = xv * gl[k];
        }
        ar[ks] = cvt8(vr); ag[ks] = cvt8(vg);
    }
    f32x4 acc[4];
    // q (gated, transposed, pre-scaled SCALE2)
    #pragma unroll
    for (int cb = 0; cb < 4; ++cb) acc[cb] = (f32x4){0.f, 0.f, 0.f, 0.f};
    gemm16T(ag, Wq, l16, quad, acc);
    store_bnc_T(qb, b, n, quad, acc, bq, SCALE2);
    // k (gated, transposed)
    #pragma unroll
    for (int cb = 0; cb < 4; ++cb) acc[cb] = (f32x4){0.f, 0.f, 0.f, 0.f};
    gemm16T(ag, Wk, l16, quad, acc);
    store_bnc_T(kb, b, n, quad, acc, bk, 1.f);
    // v (gated, normal) -> transposed bf16 BCHW
    #pragma unroll
    for (int cb = 0; cb < 4; ++cb) acc[cb] = (f32x4){0.f, 0.f, 0.f, 0.f};
    gemm16(ag, Wv, l16, quad, acc);
    store_bchw_bf16(vb, b, nb, l16, acc, bv);
    // o (ungated, normal) -> xV fp32 BNC + transposed bf16 BCHW
    #pragma unroll
    for (int cb = 0; cb < 4; ++cb) acc[cb] = (f32x4){0.f, 0.f, 0.f, 0.f};
    gemm16(ar, Wo, l16, quad, acc);
    #pragma unroll
    for (int cb = 0; cb < 4; ++cb) {
        int col = cb * 16 + l16;
        float bb = bo[col];
        ushort4 pk;
        float y0 = acc[cb][0] + bb, y1 = acc[cb][1] + bb, y2 = acc[cb][2] + bb, y3 = acc[cb][3] + bb;
        xV[((size_t)(b * Np + nb + 0)) * Cn + col] = y0;
        xV[((size_t)(b * Np + nb + 1)) * Cn + col] = y1;
        xV[((size_t)(b * Np + nb + 2)) * Cn + col] = y2;
        xV[((size_t)(b * Np + nb + 3)) * Cn + col] = y3;
        pk.x = f2bf(y0); pk.y = f2bf(y1); pk.z = f2bf(y2); pk.w = f2bf(y3);
        *(ushort4*)(xVtb + ((size_t)(b * Cn + col)) * Np + nb) = pk;
    }
}

// ---------------------------------------------------------------- combine(attn1)+Wl -> xKb (MFMA, transposed)
__global__ __launch_bounds__(256) void wl_mfma(
    const float* __restrict__ Op, const float* __restrict__ Lp,
    const float* __restrict__ Wl, const float* __restrict__ bl, ushort_t* __restrict__ xKb) {
    __shared__ float xs[64 * 65];
    __shared__ float linv[64];
    int b = blockIdx.y, n0 = blockIdx.x * 64, t = threadIdx.x;
    int wv_ = t >> 6, lane = t & 63, l16 = lane & 15, quad = lane >> 4;
    if (t < 64) {
        size_t li = (size_t)b * Np + n0 + t;
        linv[t] = 1.f / (Lp[li] + Lp[(size_t)Bn * Np + li]);
    }
    __syncthreads();
    stage_comb(Op, linv, b, n0, t, xs);
    __syncthreads();
    bf16x8 af[2];
    aload(xs, wv_ * 16 + l16, quad, af);
    f32x4 acc[4];
    #pragma unroll
    for (int cb = 0; cb < 4; ++cb) acc[cb] = (f32x4){0.f, 0.f, 0.f, 0.f};
    gemm16T(af, Wl, l16, quad, acc);
    store_bnc_T(xKb, b, n0 + wv_ * 16 + l16, quad, acc, bl, 1.f);
}

// ---------------------------------------------------------------- fused strip-convs + combined 1x1 -> xQb
// dwpair computed during staging (xp is L2-hot); n-tile == image row blockIdx.x.
__global__ __launch_bounds__(256) void hpg_mfma(
    const float* __restrict__ xp,
    const float* __restrict__ wv5, const float* __restrict__ bv5,
    const float* __restrict__ wh5, const float* __restrict__ bh5,
    const float* __restrict__ Wc1, const float* __restrict__ Wc2, const float* __restrict__ bcv,
    ushort_t* __restrict__ xQb) {
    __shared__ float xs1[64 * 65];
    __shared__ float xs2[64 * 65];
    int b = blockIdx.y, i = blockIdx.x, n0 = i * 64, t = threadIdx.x;
    int wv_ = t >> 6, lane = t & 63, l16 = lane & 15, quad = lane >> 4;
    #pragma unroll
    for (int u = 0; u < 16; ++u) {
        int idx = t + u * 256;
        int c = idx >> 6, j = idx & 63;
        const float* base = xp + ((size_t)(b * Cn + c)) * Np + i * 64 + j;
        float accV = bv5[c], accH = bh5[c];
        #pragma unroll
        for (int d = 0; d < 5; ++d) {
            int ii = i + d - 2;
            if (ii >= 0 && ii < 64) accV += wv5[c * 5 + d] * base[(d - 2) * 64];
            int jj = j + d - 2;
            if (jj >= 0 && jj < 64) accH += wh5[c * 5 + d] * base[d - 2];
        }
        xs1[c * 65 + j] = gelu_exact(accV);
        xs2[c * 65 + j] = gelu_exact(accH);
    }
    __syncthreads();
    bf16x8 a1[2], a2[2];
    int row = wv_ * 16 + l16;
    aload(xs1, row, quad, a1);
    aload(xs2, row, quad, a2);
    f32x4 acc[4];
    #pragma unroll
    for (int cb = 0; cb < 4; ++cb) acc[cb] = (f32x4){0.f, 0.f, 0.f, 0.f};
    gemm16T(a1, Wc1, l16, quad, acc);
    gemm16T(a2, Wc2, l16, quad, acc);
    store_bnc_T(xQb, b, n0 + wv_ * 16 + l16, quad, acc, bcv, 1.f);
}

// ---------------------------------------------------------------- combine(attn2)+Wp+res+LayerNorm -> BCHW (MFMA)
__global__ __launch_bounds__(256) void linln_mfma(
    const float* __restrict__ Op, const float* __restrict__ Lp,
    const float* __restrict__ Wp, const float* __restrict__ bp,
    const float* __restrict__ xV, const float* __restrict__ g, const float* __restrict__ beta,
    float* __restrict__ out) {
    __shared__ float xs[64 * 65];
    __shared__ float linv[64];
    int b = blockIdx.y, n0 = blockIdx.x * 64, t = threadIdx.x;
    int wv_ = t >> 6, lane = t & 63, l16 = lane & 15, quad = lane >> 4;
    if (t < 64) {
        size_t li = (size_t)b * Np + n0 + t;
        linv[t] = 1.f / (Lp[li] + Lp[(size_t)Bn * Np + li]);
    }
    __syncthreads();
    stage_comb(Op, linv, b, n0, t, xs);
    __syncthreads();
    bf16x8 af[2];
    aload(xs, wv_ * 16 + l16, quad, af);
    f32x4 acc[4];
    #pragma unroll
    for (int cb = 0; cb < 4; ++cb) acc[cb] = (f32x4){0.f, 0.f, 0.f, 0.f};
    gemm16(af, Wp, l16, quad, acc);
    int nb = n0 + wv_ * 16 + quad * 4;
    float vals[4][4], gc[4], bec[4];
    #pragma unroll
    for (int cb = 0; cb < 4; ++cb) {
        int col = cb * 16 + l16;
        float bb = bp[col];
        gc[cb] = g[col]; bec[cb] = beta[col];
        #pragma unroll
        for (int r = 0; r < 4; ++r)
            vals[cb][r] = acc[cb][r] + bb + xV[((size_t)(b * Np + nb + r)) * Cn + col];
    }
    f32x4 yn[4];
    #pragma unroll
    for (int r = 0; r < 4; ++r) {
        float s = 0.f, s2 = 0.f;
        #pragma unroll
        for (int cb = 0; cb < 4; ++cb) { s += vals[cb][r]; s2 += vals[cb][r] * vals[cb][r]; }
        #pragma unroll
        for (int off = 1; off < 16; off <<= 1) {
            s  += __shfl_xor(s, off, 64);
            s2 += __shfl_xor(s2, off, 64);
        }
        float mu  = s * (1.f / 64.f);
        float var = s2 * (1.f / 64.f) - mu * mu;
        float ivs = rsqrtf(var + 1e-5f);
        #pragma unroll
        for (int cb = 0; cb < 4; ++cb)
            yn[cb][r] = (vals[cb][r] - mu) * ivs * gc[cb] + bec[cb];
    }
    #pragma unroll
    for (int cb = 0; cb < 4; ++cb)
        *(f32x4*)(out + ((size_t)(b * Cn + cb * 16 + l16)) * Np + nb) = yn[cb];
}

// ---------------------------------------------------------------- fused dw3x3+GELU + 1x1 + residual -> BCHW
__global__ __launch_bounds__(256) void dsc_mfma(
    const float* __restrict__ pn, const float* __restrict__ dw, const float* __restrict__ dwb,
    const float* __restrict__ W, const float* __restrict__ bias, float* __restrict__ out) {
    __shared__ float xs[64 * 65];
    int b = blockIdx.y, i = blockIdx.x, n0 = i * 64, t = threadIdx.x;
    int wv_ = t >> 6, lane = t & 63, l16 = lane & 15, quad = lane >> 4;
    #pragma unroll
    for (int u = 0; u < 16; ++u) {
        int idx = t + u * 256;
        int c = idx >> 6, j = idx & 63;
        const float* base = pn + ((size_t)(b * Cn + c)) * Np + i * 64 + j;
        float acc = dwb[c];
        #pragma unroll
        for (int dy = 0; dy < 3; ++dy) {
            int ii = i + dy - 1;
            if (ii < 0 || ii >= 64) continue;
            #pragma unroll
            for (int dx = 0; dx < 3; ++dx) {
                int jj = j + dx - 1;
                if (jj < 0 || jj >= 64) continue;
                acc += dw[c * 9 + dy * 3 + dx] * base[(dy - 1) * 64 + (dx - 1)];
            }
        }
        xs[c * 65 + j] = gelu_exact(acc);
    }
    __syncthreads();
    bf16x8 af[2];
    aload(xs, wv_ * 16 + l16, quad, af);
    f32x4 acc[4];
    #pragma unroll
    for (int cb = 0; cb < 4; ++cb) acc[cb] = (f32x4){0.f, 0.f, 0.f, 0.f};
    gemm16(af, W, l16, quad, acc);
    int nb = n0 + wv_ * 16 + quad * 4;
    #pragma unroll
    for (int cb = 0; cb < 4; ++cb) {
        int col = cb * 16 + l16;
        float bb = bias[col];
        size_t oi = ((size_t)(b * Cn + col)) * Np + nb;
        f32x4 rv = *(const f32x4*)(pn + oi);
        f32x4 v4;
        #pragma unroll
        for (int r = 0; r < 4; ++r) v4[r] = acc[cb][r] + bb + rv[r];
        *(f32x4*)(out + oi) = v4;
    }
}

// ---------------------------------------------------------------- MFMA flash attention, 2 KV tiles/barrier
__global__ __launch_bounds__(128, 2) void attn_mfma_kernel(
    const ushort_t* __restrict__ Qb, const ushort_t* __restrict__ Kb,
    const ushort_t* __restrict__ Vtb, float* __restrict__ Opart, float* __restrict__ Lpart) {
    __shared__ ushort_t kt[2][64 * 64];    // [tile][kv][c], swizzled 16B chunks
    __shared__ ushort_t vt[2][64 * 64];    // [tile][d][kv], swizzled 16B chunks
    __shared__ ushort_t ptile[2 * 16 * 72];
    int b     = blockIdx.y;
    int qt    = blockIdx.x >> 1;
    int split = blockIdx.x & 1;
    int n0    = qt * 32;
    int t     = threadIdx.x;           // 0..127
    int wave  = t >> 6, lane = t & 63;
    int l16   = lane & 15, quad = lane >> 4;
    int sw    = l16 & 7;

    const ushort_t* qp = Qb + ((size_t)(b * Np) + n0 + wave * 16 + l16) * Cn + quad * 8;
    bf16x8 aq0 = *(const bf16x8*)(qp);
    bf16x8 aq1 = *(const bf16x8*)(qp + 32);

    f32x4 oa[4];
    float psum[4];
    #pragma unroll
    for (int cb = 0; cb < 4; ++cb) oa[cb] = (f32x4){0.f, 0.f, 0.f, 0.f};
    #pragma unroll
    for (int r = 0; r < 4; ++r) psum[r] = 0.f;

    int lrow = lane >> 3;
    int jsw  = (lane & 7) ^ (lrow & 7);
    int kvbase = split * (Np / NSPLIT);
    const ushort_t* Kg = Kb  + ((size_t)b * Np) * Cn;
    const ushort_t* Vg = Vtb + ((size_t)b * Cn) * Np;
    ushort_t* ptw = ptile + wave * 16 * 72;

    for (int m = 0; m < Np / NSPLIT / 128; ++m) {   // 16 iterations, 128 kv each
        int k0 = kvbase + m * 128;
        if (wave == 0) {                            // wave0 stages K for both tiles
            #pragma unroll
            for (int u = 0; u < 8; ++u)
                gload_lds16(Kg + ((size_t)(k0 + u * 8 + lrow)) * Cn + jsw * 8, kt[0] + u * 512);
            #pragma unroll
            for (int u = 0; u < 8; ++u)
                gload_lds16(Kg + ((size_t)(k0 + 64 + u * 8 + lrow)) * Cn + jsw * 8, kt[1] + u * 512);
        } else {                                    // wave1 stages V for both tiles
            #pragma unroll
            for (int u = 0; u < 8; ++u)
                gload_lds16(Vg + ((size_t)(u * 8 + lrow)) * Np + k0 + jsw * 8, vt[0] + u * 512);
            #pragma unroll
            for (int u = 0; u < 8; ++u)
                gload_lds16(Vg + ((size_t)(u * 8 + lrow)) * Np + k0 + 64 + jsw * 8, vt[1] + u * 512);
        }
        __syncthreads();
        #pragma unroll
        for (int tb = 0; tb < 2; ++tb) {
            const ushort_t* ktc = kt[tb];
            const ushort_t* vtc = vt[tb];
            f32x4 sa[4];
            #pragma unroll
            for (int cb = 0; cb < 4; ++cb) sa[cb] = (f32x4){0.f, 0.f, 0.f, 0.f};
            #pragma unroll
            for (int cb = 0; cb < 4; ++cb) {
                const ushort_t* krow = ktc + (cb * 16 + l16) * 64;
                bf16x8 bk0 = *(const bf16x8*)(krow + ((quad    ) ^ sw) * 8);
                bf16x8 bk1 = *(const bf16x8*)(krow + ((quad + 4) ^ sw) * 8);
                sa[cb] = __builtin_amdgcn_mfma_f32_16x16x32_bf16(aq0, bk0, sa[cb], 0, 0, 0);
                sa[cb] = __builtin_amdgcn_mfma_f32_16x16x32_bf16(aq1, bk1, sa[cb], 0, 0, 0);
            }
            #pragma unroll
            for (int r = 0; r < 4; ++r) {
                #pragma unroll
                for (int cb = 0; cb < 4; ++cb) {
                    float p = exp2f(sa[cb][r]);
                    ptw[(quad * 4 + r) * 72 + cb * 16 + l16] = f2bf(p);
                    psum[r] += p;
                }
            }
            asm volatile("s_waitcnt lgkmcnt(0)" ::: "memory");
            #pragma unroll
            for (int ks = 0; ks < 2; ++ks) {
                bf16x8 ap = *(const bf16x8*)(ptw + l16 * 72 + ks * 32 + quad * 8);
                #pragma unroll
                for (int cb = 0; cb < 4; ++cb) {
                    const ushort_t* vrow = vtc + (cb * 16 + l16) * 64;
                    bf16x8 bv = *(const bf16x8*)(vrow + ((ks * 4 + quad) ^ sw) * 8);
                    oa[cb] = __builtin_amdgcn_mfma_f32_16x16x32_bf16(ap, bv, oa[cb], 0, 0, 0);
                }
            }
        }
        __syncthreads();
    }
    size_t obase = ((size_t)(split * Bn + b)) * Np;
    #pragma unroll
    for (int r = 0; r < 4; ++r) {
        float s = psum[r];
        s += __shfl_xor(s, 1, 64);
        s += __shfl_xor(s, 2, 64);
        s += __shfl_xor(s, 4, 64);
        s += __shfl_xor(s, 8, 64);
        int row = n0 + wave * 16 + quad * 4 + r;
        if (l16 == 0) Lpart[obase + row] = s;
        #pragma unroll
        for (int cb = 0; cb < 4; ++cb)
            Opart[(obase + row) * Cn + cb * 16 + l16] = oa[cb][r];
    }
}

// ---------------------------------------------------------------- bilinear x2 upsample
__global__ void upsample_kernel(const float* __restrict__ in, float* __restrict__ out) {
    int idx = blockIdx.x * 256 + threadIdx.x;
    int x  = idx & 127;
    int y  = (idx >> 7) & 127;
    int bc = idx >> 14;
    float sy = y * (63.f / 127.f);
    float sx = x * (63.f / 127.f);
    int y0 = (int)sy, x0 = (int)sx;
    float fy = sy - y0, fx = sx - x0;
    int y1 = min(y0 + 1, 63), x1 = min(x0 + 1, 63);
    const float* p = in + (size_t)bc * Np;
    float v00 = p[y0 * 64 + x0], v01 = p[y0 * 64 + x1];
    float v10 = p[y1 * 64 + x0], v11 = p[y1 * 64 + x1];
    out[idx] = (v00 * (1.f - fx) + v01 * fx) * (1.f - fy) +
               (v10 * (1.f - fx) + v11 * fx) * fy;
}

// ----------------------------------------------------------------
extern "C" void kernel_launch(void* const* d_in, const int* in_sizes, int n_in,
                              void* d_out, int out_size, void* d_ws, size_t ws_size,
                              hipStream_t stream) {
    const float* x       = (const float*)d_in[0];
    const float* Wq      = (const float*)d_in[1];
    const float* bq      = (const float*)d_in[2];
    const float* Wk      = (const float*)d_in[3];
    const float* bk      = (const float*)d_in[4];
    const float* Wv      = (const float*)d_in[5];
    const float* bv      = (const float*)d_in[6];
    const float* Wl      = (const float*)d_in[7];
    const float* bl      = (const float*)d_in[8];
    const float* Wo      = (const float*)d_in[9];
    const float* bo      = (const float*)d_in[10];
    const float* Wp      = (const float*)d_in[11];
    const float* bp      = (const float*)d_in[12];
    const float* sch_dw  = (const float*)d_in[13];
    const float* sch_dwb = (const float*)d_in[14];
    const float* sch_pw  = (const float*)d_in[15];
    const float* sch_pwb = (const float*)d_in[16];
    const float* scv_dw  = (const float*)d_in[17];
    const float* scv_dwb = (const float*)d_in[18];
    const float* scv_pw  = (const float*)d_in[19];
    const float* scv_pwb = (const float*)d_in[20];
    const float* convh_w = (const float*)d_in[21];
    const float* convh_b = (const float*)d_in[22];
    const float* dsc_dw  = (const float*)d_in[23];
    const float* dsc_dwb = (const float*)d_in[24];
    const float* dsc_pw  = (const float*)d_in[25];
    const float* dsc_pwb = (const float*)d_in[26];
    const float* ln_g    = (const float*)d_in[27];
    const float* ln_b    = (const float*)d_in[28];

    float* ws = (float*)d_ws;
    const size_t SZ = (size_t)Bn * Np * Cn;   // 1,048,576 elements
    float* xp   = ws;                 // pooled input BCHW; later p_norm
    float* xV   = ws + SZ;            // BNC fp32
    float* Op   = ws + 2 * SZ;        // 2*SZ attn partials; Op+SZ doubles as dsc output
    float* dscO = Op + SZ;
    ushort_t* bws  = (ushort_t*)(ws + 4 * SZ);
    ushort_t* qb   = bws;             // bf16 BNC (pre-scaled SCALE2)
    ushort_t* kb_  = bws + SZ;        // bf16 BNC
    ushort_t* vb   = bws + 2 * SZ;    // bf16 BCHW (V^T)
    ushort_t* xKb  = bws + 3 * SZ;    // bf16 BNC
    ushort_t* xVtb = bws + 4 * SZ;    // bf16 BCHW (V^T)
    ushort_t* xQb  = bws + 5 * SZ;    // bf16 BNC (pre-scaled SCALE2)
    float* gap4k  = ws + 7 * SZ;                    // 4096 per-block partials
    float* Lpart  = gap4k + 4096;                   // NSPLIT*Bn*Np = 32768
    float* Wc1  = Lpart + (size_t)NSPLIT * Bn * Np; // 4096
    float* Wc2  = Wc1 + 4096;                       // 4096
    float* bcv  = Wc2 + 4096;                       // 64

    dim3 g64(64, Bn);
    dim3 ga((Np / 32) * NSPLIT, Bn);

    // avgpool + GAP partials + (merged) weight combine
    avgpool_kernel<<<4096 + 32, 256, 0, stream>>>(x, xp, gap4k,
                                                  convh_w, convh_b, sch_pw, sch_pwb,
                                                  scv_pw, scv_pwb, Wc1, Wc2, bcv);
    // q,k,v + x_V (4 GEMMs, MFMA)
    qkv_mfma<<<g64, 256, 0, stream>>>(xp, gap4k, Wq, bq, Wk, bk, Wv, bv, Wo, bo,
                                      qb, kb_, vb, xV, xVtb);
    // attention 1
    attn_mfma_kernel<<<ga, 128, 0, stream>>>(qb, kb_, vb, Op, Lpart);
    // x_K = linear(combine(attn1), Wl)
    wl_mfma<<<g64, 256, 0, stream>>>(Op, Lpart, Wl, bl, xKb);
    // x_Q = combined strip-conv + 1x1 (dwpair fused into staging, SCALE2 folded)
    hpg_mfma<<<g64, 256, 0, stream>>>(xp, sch_dw, sch_dwb, scv_dw, scv_dwb,
                                      Wc1, Wc2, bcv, xQb);
    // attention 2
    attn_mfma_kernel<<<ga, 128, 0, stream>>>(xQb, xKb, xVtb, Op, Lpart);
    // prompt = linear(combine, Wp) + x_V ; LN ; -> BCHW (xp reused as p_norm)
    linln_mfma<<<g64, 256, 0, stream>>>(Op, Lpart, Wp, bp, xV, ln_g, ln_b, xp);
    // dsc: dw3x3+gelu fused into staging, 1x1 + residual
    dsc_mfma<<<g64, 256, 0, stream>>>(xp, dsc_dw, dsc_dwb, dsc_pw, dsc_pwb, dscO);
    // bilinear x2
    upsample_kernel<<<16384, 256, 0, stream>>>(dscO, (float*)d_out);
}

// Round 8
// 281.249 us; speedup vs baseline: 1.1828x; 1.1828x over previous
//
#include <hip/hip_runtime.h>
#include <math.h>

// Problem constants
#define Bn 4
#define Cn 64
#define Np 4096   // 64*64
#define NSPLIT 2
// SCALE * log2(e): folded into all Q pre-scales; attention uses exp2f (native v_exp_f32)
#define SCALE2 0.18033688011112042f

typedef unsigned short ushort_t;
typedef __attribute__((ext_vector_type(4))) float f32x4;
typedef __attribute__((ext_vector_type(8))) short bf16x8;
typedef __attribute__((ext_vector_type(4))) short bf16x4;

__device__ __forceinline__ float gelu_exact(float x) {
    return 0.5f * x * (1.0f + erff(x * 0.70710678118654752440f));
}
__device__ __forceinline__ ushort_t f2bf(float f) {       // RNE float->bf16
    unsigned int u = __float_as_uint(f);
    u += 0x7fffu + ((u >> 16) & 1u);
    return (ushort_t)(u >> 16);
}
__device__ __forceinline__ void gload_lds16(const ushort_t* g, ushort_t* l) {
    __builtin_amdgcn_global_load_lds(
        (const __attribute__((address_space(1))) void*)g,
        (__attribute__((address_space(3))) void*)l, 16, 0, 0);
}
__device__ __forceinline__ bf16x8 cvt8(const float v[8]) {
    bf16x8 r;
    #pragma unroll
    for (int j = 0; j < 8; ++j) r[j] = (short)f2bf(v[j]);
    return r;
}
// Normal orientation: D[n][o] — A = x rows, B = W rows. acc C-layout: row=n, col=o.
__device__ __forceinline__ void gemm16(const bf16x8 af[2], const float* __restrict__ W,
                                       int l16, int quad, f32x4* acc) {
    #pragma unroll
    for (int cb = 0; cb < 4; ++cb) {
        #pragma unroll
        for (int ks = 0; ks < 2; ++ks) {
            const float* p = W + (cb * 16 + l16) * 64 + ks * 32 + quad * 8;
            float v[8];
            #pragma unroll
            for (int j = 0; j < 8; ++j) v[j] = p[j];
            acc[cb] = __builtin_amdgcn_mfma_f32_16x16x32_bf16(af[ks], cvt8(v), acc[cb], 0, 0, 0);
        }
    }
}
// Transposed orientation: D[o][n]. acc C: row=o_sub, col=n -> ushort4 channel-packed stores.
__device__ __forceinline__ void gemm16T(const bf16x8 af[2], const float* __restrict__ W,
                                        int l16, int quad, f32x4* acc) {
    #pragma unroll
    for (int cb = 0; cb < 4; ++cb) {
        #pragma unroll
        for (int ks = 0; ks < 2; ++ks) {
            const float* p = W + (cb * 16 + l16) * 64 + ks * 32 + quad * 8;
            float v[8];
            #pragma unroll
            for (int j = 0; j < 8; ++j) v[j] = p[j];
            acc[cb] = __builtin_amdgcn_mfma_f32_16x16x32_bf16(cvt8(v), af[ks], acc[cb], 0, 0, 0);
        }
    }
}
__device__ __forceinline__ void aload(const float* xs, int row, int quad, bf16x8 af[2]) {
    #pragma unroll
    for (int ks = 0; ks < 2; ++ks) {
        float v[8];
        #pragma unroll
        for (int j = 0; j < 8; ++j) v[j] = xs[(ks * 32 + quad * 8 + j) * 65 + row];
        af[ks] = cvt8(v);
    }
}
__device__ __forceinline__ void stage_bchw(const float* __restrict__ X, int b, int n0, int t,
                                           float* xs) {
    #pragma unroll
    for (int u = 0; u < 16; ++u) {
        int idx = t + u * 256;
        int c = idx >> 6, nl = idx & 63;
        xs[c * 65 + nl] = X[((size_t)(b * Cn + c)) * Np + n0 + nl];
    }
}
__device__ __forceinline__ void stage_comb(const float* __restrict__ Op, const float* linv,
                                           int b, int n0, int t, float* xs) {
    const size_t SS = (size_t)Bn * Np * Cn;
    #pragma unroll
    for (int u = 0; u < 16; ++u) {
        int idx = t + u * 256;
        int nl = idx >> 6, c = idx & 63;
        size_t gi = ((size_t)(b * Np + n0 + nl)) * Cn + c;
        xs[c * 65 + nl] = (Op[gi] + Op[SS + gi]) * linv[nl];
    }
}
__device__ __forceinline__ void store_bnc_T(ushort_t* __restrict__ Y, int b, int n, int quad,
                                            const f32x4* acc, const float* __restrict__ bias,
                                            float mult) {
    #pragma unroll
    for (int cb = 0; cb < 4; ++cb) {
        int o0 = cb * 16 + quad * 4;
        ushort4 pk;
        pk.x = f2bf((acc[cb][0] + bias[o0 + 0]) * mult);
        pk.y = f2bf((acc[cb][1] + bias[o0 + 1]) * mult);
        pk.z = f2bf((acc[cb][2] + bias[o0 + 2]) * mult);
        pk.w = f2bf((acc[cb][3] + bias[o0 + 3]) * mult);
        *(ushort4*)(Y + ((size_t)(b * Np + n)) * Cn + o0) = pk;
    }
}
__device__ __forceinline__ void store_bchw_bf16(ushort_t* __restrict__ Y, int b, int nb, int l16,
                                                const f32x4* acc, const float* __restrict__ bias) {
    #pragma unroll
    for (int cb = 0; cb < 4; ++cb) {
        int col = cb * 16 + l16;
        float bb = bias[col];
        ushort4 pk;
        pk.x = f2bf(acc[cb][0] + bb); pk.y = f2bf(acc[cb][1] + bb);
        pk.z = f2bf(acc[cb][2] + bb); pk.w = f2bf(acc[cb][3] + bb);
        *(ushort4*)(Y + ((size_t)(b * Cn + col)) * Np + nb) = pk;
    }
}

// ---------------------------------------------------------------- avgpool 2x2 + GAP partials + wcomb
__global__ void avgpool_kernel(const float* __restrict__ x, float* __restrict__ xp,
                               float* __restrict__ gap4k,
                               const float* __restrict__ convh_w, const float* __restrict__ convh_b,
                               const float* __restrict__ sch_pw, const float* __restrict__ sch_pwb,
                               const float* __restrict__ scv_pw, const float* __restrict__ scv_pwb,
                               float* __restrict__ Wc1, float* __restrict__ Wc2,
                               float* __restrict__ bcv) {
    if (blockIdx.x < 4096) {
        int idx = blockIdx.x * 256 + threadIdx.x;
        int j  = idx & 63;
        int i  = (idx >> 6) & 63;
        int bc = idx >> 12;
        const float* p = x + ((size_t)bc * 128 + 2 * i) * 128 + 2 * j;
        float v = 0.25f * (p[0] + p[1] + p[128] + p[129]);
        xp[idx] = v;
        float s = v;
        #pragma unroll
        for (int off = 1; off < 64; off <<= 1) s += __shfl_xor(s, off, 64);
        __shared__ float sm[4];
        if ((threadIdx.x & 63) == 0) sm[threadIdx.x >> 6] = s;
        __syncthreads();
        if (threadIdx.x == 0) gap4k[blockIdx.x] = sm[0] + sm[1] + sm[2] + sm[3];
    } else {
        int g = (blockIdx.x - 4096) * 256 + threadIdx.x;   // 8192 threads
        int sel = g >> 12, idx = g & 4095;
        int o = idx >> 6, c = idx & 63;
        const float* pw = sel ? scv_pw : sch_pw;
        float acc = 0.f;
        #pragma unroll 8
        for (int m = 0; m < 64; ++m) acc += convh_w[o * 64 + m] * pw[m * 64 + c];
        (sel ? Wc2 : Wc1)[idx] = acc * SCALE2;
        if (g < 64) {
            float ab = convh_b[g];
            for (int m = 0; m < 64; ++m) ab += convh_w[g * 64 + m] * (sch_pwb[m] + scv_pwb[m]);
            bcv[g] = ab * SCALE2;
        }
    }
}

// ---------------------------------------------------------------- fused QKV + Wo (MFMA, 4 GEMMs)
__global__ __launch_bounds__(256) void qkv_mfma(
    const float* __restrict__ xp, const float* __restrict__ gap4k,
    const float* __restrict__ Wq, const float* __restrict__ bq,
    const float* __restrict__ Wk, const float* __restrict__ bk,
    const float* __restrict__ Wv, const float* __restrict__ bv,
    const float* __restrict__ Wo, const float* __restrict__ bo,
    ushort_t* __restrict__ qb, ushort_t* __restrict__ kb, ushort_t* __restrict__ vb,
    float* __restrict__ xV, ushort_t* __restrict__ xVtb) {
    __shared__ float xs[64 * 65];
    __shared__ float gl[64];
    int b = blockIdx.y, n0 = blockIdx.x * 64, t = threadIdx.x;
    int wv_ = t >> 6, lane = t & 63, l16 = lane & 15, quad = lane >> 4;
    stage_bchw(xp, b, n0, t, xs);
    if (t < 64) {
        float s = 0.f;
        #pragma unroll
        for (int u = 0; u < 16; ++u) s += gap4k[(b * 64 + t) * 16 + u];
        gl[t] = s * (1.f / 4096.f);
    }
    __syncthreads();
    int row = wv_ * 16 + l16;
    int n   = n0 + wv_ * 16 + l16;
    int nb  = n0 + wv_ * 16 + quad * 4;
    bf16x8 ar[2], ag[2];
    #pragma unroll
    for (int ks = 0; ks < 2; ++ks) {
        float vr[8], vg[8];
        #pragma unroll
        for (int j = 0; j < 8; ++j) {
            int k = ks * 32 + quad * 8 + j;
            float xv = xs[k * 65 + row];
            vr[j] = xv; vg[j] = xv * gl[k];
        }
        ar[ks] = cvt8(vr); ag[ks] = cvt8(vg);
    }
    f32x4 acc[4];
    #pragma unroll
    for (int cb = 0; cb < 4; ++cb) acc[cb] = (f32x4){0.f, 0.f, 0.f, 0.f};
    gemm16T(ag, Wq, l16, quad, acc);
    store_bnc_T(qb, b, n, quad, acc, bq, SCALE2);
    #pragma unroll
    for (int cb = 0; cb < 4; ++cb) acc[cb] = (f32x4){0.f, 0.f, 0.f, 0.f};
    gemm16T(ag, Wk, l16, quad, acc);
    store_bnc_T(kb, b, n, quad, acc, bk, 1.f);
    #pragma unroll
    for (int cb = 0; cb < 4; ++cb) acc[cb] = (f32x4){0.f, 0.f, 0.f, 0.f};
    gemm16(ag, Wv, l16, quad, acc);
    store_bchw_bf16(vb, b, nb, l16, acc, bv);
    #pragma unroll
    for (int cb = 0; cb < 4; ++cb) acc[cb] = (f32x4){0.f, 0.f, 0.f, 0.f};
    gemm16(ar, Wo, l16, quad, acc);
    #pragma unroll
    for (int cb = 0; cb < 4; ++cb) {
        int col = cb * 16 + l16;
        float bb = bo[col];
        ushort4 pk;
        float y0 = acc[cb][0] + bb, y1 = acc[cb][1] + bb, y2 = acc[cb][2] + bb, y3 = acc[cb][3] + bb;
        xV[((size_t)(b * Np + nb + 0)) * Cn + col] = y0;
        xV[((size_t)(b * Np + nb + 1)) * Cn + col] = y1;
        xV[((size_t)(b * Np + nb + 2)) * Cn + col] = y2;
        xV[((size_t)(b * Np + nb + 3)) * Cn + col] = y3;
        pk.x = f2bf(y0); pk.y = f2bf(y1); pk.z = f2bf(y2); pk.w = f2bf(y3);
        *(ushort4*)(xVtb + ((size_t)(b * Cn + col)) * Np + nb) = pk;
    }
}

// ---------------------------------------------------------------- combine(attn1)+Wl -> xKb
__global__ __launch_bounds__(256) void wl_mfma(
    const float* __restrict__ Op, const float* __restrict__ Lp,
    const float* __restrict__ Wl, const float* __restrict__ bl, ushort_t* __restrict__ xKb) {
    __shared__ float xs[64 * 65];
    __shared__ float linv[64];
    int b = blockIdx.y, n0 = blockIdx.x * 64, t = threadIdx.x;
    int wv_ = t >> 6, lane = t & 63, l16 = lane & 15, quad = lane >> 4;
    if (t < 64) {
        size_t li = (size_t)b * Np + n0 + t;
        linv[t] = 1.f / (Lp[li] + Lp[(size_t)Bn * Np + li]);
    }
    __syncthreads();
    stage_comb(Op, linv, b, n0, t, xs);
    __syncthreads();
    bf16x8 af[2];
    aload(xs, wv_ * 16 + l16, quad, af);
    f32x4 acc[4];
    #pragma unroll
    for (int cb = 0; cb < 4; ++cb) acc[cb] = (f32x4){0.f, 0.f, 0.f, 0.f};
    gemm16T(af, Wl, l16, quad, acc);
    store_bnc_T(xKb, b, n0 + wv_ * 16 + l16, quad, acc, bl, 1.f);
}

// ---------------------------------------------------------------- strip convs (separate, R6 form)
__global__ void dwpair_kernel(const float* __restrict__ xp,
                              const float* __restrict__ wv5, const float* __restrict__ bv5,
                              const float* __restrict__ wh5, const float* __restrict__ bh5,
                              float* __restrict__ gh, float* __restrict__ gv) {
    int idx = blockIdx.x * 256 + threadIdx.x;
    int j = idx & 63, i = (idx >> 6) & 63, bc = idx >> 12, c = bc & 63;
    const float* p = xp + (size_t)bc * Np;
    float accV = bv5[c], accH = bh5[c];
    #pragma unroll
    for (int d = 0; d < 5; ++d) {
        int ii = i + d - 2;
        if (ii >= 0 && ii < 64) accV += wv5[c * 5 + d] * p[ii * 64 + j];
        int jj = j + d - 2;
        if (jj >= 0 && jj < 64) accH += wh5[c * 5 + d] * p[i * 64 + jj];
    }
    gh[idx] = gelu_exact(accV);
    gv[idx] = gelu_exact(accH);
}

__global__ void dw3x3_gelu_kernel(const float* __restrict__ xin, const float* __restrict__ w,
                                  const float* __restrict__ bias, float* __restrict__ out) {
    int idx = blockIdx.x * 256 + threadIdx.x;
    int j = idx & 63, i = (idx >> 6) & 63, bc = idx >> 12, c = bc & 63;
    const float* p = xin + (size_t)bc * Np;
    float acc = bias[c];
    #pragma unroll
    for (int dy = 0; dy < 3; ++dy) {
        int ii = i + dy - 1;
        if (ii < 0 || ii >= 64) continue;
        #pragma unroll
        for (int dx = 0; dx < 3; ++dx) {
            int jj = j + dx - 1;
            if (jj < 0 || jj >= 64) continue;
            acc += w[c * 9 + dy * 3 + dx] * p[ii * 64 + jj];
        }
    }
    out[idx] = gelu_exact(acc);
}

// ---------------------------------------------------------------- high-freq 1x1 (combined weights)
__global__ __launch_bounds__(256) void hpg_mfma(
    const float* __restrict__ gh, const float* __restrict__ gv,
    const float* __restrict__ Wc1, const float* __restrict__ Wc2, const float* __restrict__ bcv,
    ushort_t* __restrict__ xQb) {
    __shared__ float xs1[64 * 65];
    __shared__ float xs2[64 * 65];
    int b = blockIdx.y, n0 = blockIdx.x * 64, t = threadIdx.x;
    int wv_ = t >> 6, lane = t & 63, l16 = lane & 15, quad = lane >> 4;
    stage_bchw(gh, b, n0, t, xs1);
    stage_bchw(gv, b, n0, t, xs2);
    __syncthreads();
    bf16x8 a1[2], a2[2];
    int row = wv_ * 16 + l16;
    aload(xs1, row, quad, a1);
    aload(xs2, row, quad, a2);
    f32x4 acc[4];
    #pragma unroll
    for (int cb = 0; cb < 4; ++cb) acc[cb] = (f32x4){0.f, 0.f, 0.f, 0.f};
    gemm16T(a1, Wc1, l16, quad, acc);
    gemm16T(a2, Wc2, l16, quad, acc);
    store_bnc_T(xQb, b, n0 + wv_ * 16 + l16, quad, acc, bcv, 1.f);
}

// ---------------------------------------------------------------- combine(attn2)+Wp+res+LayerNorm -> BCHW
__global__ __launch_bounds__(256) void linln_mfma(
    const float* __restrict__ Op, const float* __restrict__ Lp,
    const float* __restrict__ Wp, const float* __restrict__ bp,
    const float* __restrict__ xV, const float* __restrict__ g, const float* __restrict__ beta,
    float* __restrict__ out) {
    __shared__ float xs[64 * 65];
    __shared__ float linv[64];
    int b = blockIdx.y, n0 = blockIdx.x * 64, t = threadIdx.x;
    int wv_ = t >> 6, lane = t & 63, l16 = lane & 15, quad = lane >> 4;
    if (t < 64) {
        size_t li = (size_t)b * Np + n0 + t;
        linv[t] = 1.f / (Lp[li] + Lp[(size_t)Bn * Np + li]);
    }
    __syncthreads();
    stage_comb(Op, linv, b, n0, t, xs);
    __syncthreads();
    bf16x8 af[2];
    aload(xs, wv_ * 16 + l16, quad, af);
    f32x4 acc[4];
    #pragma unroll
    for (int cb = 0; cb < 4; ++cb) acc[cb] = (f32x4){0.f, 0.f, 0.f, 0.f};
    gemm16(af, Wp, l16, quad, acc);
    int nb = n0 + wv_ * 16 + quad * 4;
    float vals[4][4], gc[4], bec[4];
    #pragma unroll
    for (int cb = 0; cb < 4; ++cb) {
        int col = cb * 16 + l16;
        float bb = bp[col];
        gc[cb] = g[col]; bec[cb] = beta[col];
        #pragma unroll
        for (int r = 0; r < 4; ++r)
            vals[cb][r] = acc[cb][r] + bb + xV[((size_t)(b * Np + nb + r)) * Cn + col];
    }
    f32x4 yn[4];
    #pragma unroll
    for (int r = 0; r < 4; ++r) {
        float s = 0.f, s2 = 0.f;
        #pragma unroll
        for (int cb = 0; cb < 4; ++cb) { s += vals[cb][r]; s2 += vals[cb][r] * vals[cb][r]; }
        #pragma unroll
        for (int off = 1; off < 16; off <<= 1) {
            s  += __shfl_xor(s, off, 64);
            s2 += __shfl_xor(s2, off, 64);
        }
        float mu  = s * (1.f / 64.f);
        float var = s2 * (1.f / 64.f) - mu * mu;
        float ivs = rsqrtf(var + 1e-5f);
        #pragma unroll
        for (int cb = 0; cb < 4; ++cb)
            yn[cb][r] = (vals[cb][r] - mu) * ivs * gc[cb] + bec[cb];
    }
    #pragma unroll
    for (int cb = 0; cb < 4; ++cb)
        *(f32x4*)(out + ((size_t)(b * Cn + cb * 16 + l16)) * Np + nb) = yn[cb];
}

// ---------------------------------------------------------------- dsc 1x1 + residual (R6 form)
__global__ __launch_bounds__(256) void dsc_mfma(
    const float* __restrict__ X, const float* __restrict__ W, const float* __restrict__ bias,
    const float* __restrict__ res, float* __restrict__ out) {
    __shared__ float xs[64 * 65];
    int b = blockIdx.y, n0 = blockIdx.x * 64, t = threadIdx.x;
    int wv_ = t >> 6, lane = t & 63, l16 = lane & 15, quad = lane >> 4;
    stage_bchw(X, b, n0, t, xs);
    __syncthreads();
    bf16x8 af[2];
    aload(xs, wv_ * 16 + l16, quad, af);
    f32x4 acc[4];
    #pragma unroll
    for (int cb = 0; cb < 4; ++cb) acc[cb] = (f32x4){0.f, 0.f, 0.f, 0.f};
    gemm16(af, W, l16, quad, acc);
    int nb = n0 + wv_ * 16 + quad * 4;
    #pragma unroll
    for (int cb = 0; cb < 4; ++cb) {
        int col = cb * 16 + l16;
        float bb = bias[col];
        size_t oi = ((size_t)(b * Cn + col)) * Np + nb;
        f32x4 rv = *(const f32x4*)(res + oi);
        f32x4 v4;
        #pragma unroll
        for (int r = 0; r < 4; ++r) v4[r] = acc[cb][r] + bb + rv[r];
        *(f32x4*)(out + oi) = v4;
    }
}

// ---------------------------------------------------------------- MFMA flash attention
// S^T orientation: mfma(A=K, B=Q) -> C-layout of S^T == B-operand layout of 16x16x16
// PV MFMA -> P stays in registers (no LDS round trip). Double-buffered global_load_lds
// prefetch: DMA for tile m+1 overlaps compute of tile m; __syncthreads drains it after.
__global__ __launch_bounds__(128, 2) void attn_mfma_kernel(
    const ushort_t* __restrict__ Qb, const ushort_t* __restrict__ Kb,
    const ushort_t* __restrict__ Vtb, float* __restrict__ Opart, float* __restrict__ Lpart) {
    __shared__ ushort_t kt[2][64 * 64];    // [buf][kv][c], swizzled 16B chunks
    __shared__ ushort_t vt[2][64 * 64];    // [buf][d][kv], swizzled 16B chunks
    int b     = blockIdx.y;
    int qt    = blockIdx.x >> 1;
    int split = blockIdx.x & 1;
    int n0    = qt * 32;
    int t     = threadIdx.x;           // 0..127
    int wave  = t >> 6, lane = t & 63;
    int l16   = lane & 15, quad = lane >> 4;
    int sw    = l16 & 7;

    // Q as B-operand: B[k=c][n=query], n=l16, k=quad*8+j (+32)
    const ushort_t* qp = Qb + ((size_t)(b * Np) + n0 + wave * 16 + l16) * Cn + quad * 8;
    bf16x8 aq0 = *(const bf16x8*)(qp);
    bf16x8 aq1 = *(const bf16x8*)(qp + 32);

    f32x4 oa[4];                       // O^T accumulators: row=d_sub, col=query
    float psum = 0.f;                  // per-lane kv-partial for query l16
    #pragma unroll
    for (int db = 0; db < 4; ++db) oa[db] = (f32x4){0.f, 0.f, 0.f, 0.f};

    int lrow = lane >> 3;
    int jsw  = (lane & 7) ^ (lrow & 7);
    int kvbase = split * (Np / NSPLIT);
    const ushort_t* Kg = Kb  + ((size_t)b * Np) * Cn;
    const ushort_t* Vg = Vtb + ((size_t)b * Cn) * Np;

    auto stage = [&](int buf, int k0) {
        if (wave == 0) {
            #pragma unroll
            for (int u = 0; u < 8; ++u)
                gload_lds16(Kg + ((size_t)(k0 + u * 8 + lrow)) * Cn + jsw * 8, kt[buf] + u * 512);
        } else {
            #pragma unroll
            for (int u = 0; u < 8; ++u)
                gload_lds16(Vg + ((size_t)(u * 8 + lrow)) * Np + k0 + jsw * 8, vt[buf] + u * 512);
        }
    };
    const int NT = Np / NSPLIT / 64;   // 32
    stage(0, kvbase);
    __syncthreads();

    for (int m = 0; m < NT; ++m) {
        int cur = m & 1;
        if (m + 1 < NT) stage(1 - cur, kvbase + (m + 1) * 64);
        const ushort_t* ktc = kt[cur];
        const ushort_t* vtc = vt[cur];

        // S^T = K Q : C row = kv_sub (quad*4+r), col = query (l16)
        f32x4 sa[4];
        #pragma unroll
        for (int cb = 0; cb < 4; ++cb) sa[cb] = (f32x4){0.f, 0.f, 0.f, 0.f};
        #pragma unroll
        for (int cb = 0; cb < 4; ++cb) {
            const ushort_t* krow = ktc + (cb * 16 + l16) * 64;
            bf16x8 bk0 = *(const bf16x8*)(krow + ((quad    ) ^ sw) * 8);
            bf16x8 bk1 = *(const bf16x8*)(krow + ((quad + 4) ^ sw) * 8);
            sa[cb] = __builtin_amdgcn_mfma_f32_16x16x32_bf16(bk0, aq0, sa[cb], 0, 0, 0);
            sa[cb] = __builtin_amdgcn_mfma_f32_16x16x32_bf16(bk1, aq1, sa[cb], 0, 0, 0);
        }
        // p = 2^s in registers; pack directly as PV B-fragments (C-layout == B-layout, K=16)
        bf16x4 pb[4];
        #pragma unroll
        for (int cb = 0; cb < 4; ++cb) {
            float p0 = exp2f(sa[cb][0]), p1 = exp2f(sa[cb][1]);
            float p2 = exp2f(sa[cb][2]), p3 = exp2f(sa[cb][3]);
            psum += (p0 + p1) + (p2 + p3);
            bf16x4 pk;
            pk[0] = (short)f2bf(p0); pk[1] = (short)f2bf(p1);
            pk[2] = (short)f2bf(p2); pk[3] = (short)f2bf(p3);
            pb[cb] = pk;
        }
        // O^T += V^T P^T : A = V^T[d][kv] (b64 LDS reads), B = pb
        #pragma unroll
        for (int kc = 0; kc < 4; ++kc) {
            #pragma unroll
            for (int db = 0; db < 4; ++db) {
                int d = db * 16 + l16;
                const ushort_t* va = vtc + d * 64 +
                    (((kc * 2 + (quad >> 1)) ^ (d & 7)) * 8) + (quad & 1) * 4;
                bf16x4 av = *(const bf16x4*)va;
                oa[db] = __builtin_amdgcn_mfma_f32_16x16x16bf16_1k(av, pb[kc], oa[db], 0, 0, 0);
            }
        }
        __syncthreads();   // readers done with buf cur + prefetch DMA (overlapped) drained
    }
    // psum: reduce across quads (same query l16)
    psum += __shfl_xor(psum, 16, 64);
    psum += __shfl_xor(psum, 32, 64);
    size_t obase = ((size_t)(split * Bn + b)) * Np;
    int n = n0 + wave * 16 + l16;
    if (quad == 0) Lpart[obase + n] = psum;
    #pragma unroll
    for (int db = 0; db < 4; ++db)
        *(f32x4*)(Opart + (obase + n) * Cn + db * 16 + quad * 4) = oa[db];
}

// ---------------------------------------------------------------- bilinear x2 upsample
__global__ void upsample_kernel(const float* __restrict__ in, float* __restrict__ out) {
    int idx = blockIdx.x * 256 + threadIdx.x;
    int x  = idx & 127;
    int y  = (idx >> 7) & 127;
    int bc = idx >> 14;
    float sy = y * (63.f / 127.f);
    float sx = x * (63.f / 127.f);
    int y0 = (int)sy, x0 = (int)sx;
    float fy = sy - y0, fx = sx - x0;
    int y1 = min(y0 + 1, 63), x1 = min(x0 + 1, 63);
    const float* p = in + (size_t)bc * Np;
    float v00 = p[y0 * 64 + x0], v01 = p[y0 * 64 + x1];
    float v10 = p[y1 * 64 + x0], v11 = p[y1 * 64 + x1];
    out[idx] = (v00 * (1.f - fx) + v01 * fx) * (1.f - fy) +
               (v10 * (1.f - fx) + v11 * fx) * fy;
}

// ----------------------------------------------------------------
extern "C" void kernel_launch(void* const* d_in, const int* in_sizes, int n_in,
                              void* d_out, int out_size, void* d_ws, size_t ws_size,
                              hipStream_t stream) {
    const float* x       = (const float*)d_in[0];
    const float* Wq      = (const float*)d_in[1];
    const float* bq      = (const float*)d_in[2];
    const float* Wk      = (const float*)d_in[3];
    const float* bk      = (const float*)d_in[4];
    const float* Wv      = (const float*)d_in[5];
    const float* bv      = (const float*)d_in[6];
    const float* Wl      = (const float*)d_in[7];
    const float* bl      = (const float*)d_in[8];
    const float* Wo      = (const float*)d_in[9];
    const float* bo      = (const float*)d_in[10];
    const float* Wp      = (const float*)d_in[11];
    const float* bp      = (const float*)d_in[12];
    const float* sch_dw  = (const float*)d_in[13];
    const float* sch_dwb = (const float*)d_in[14];
    const float* sch_pw  = (const float*)d_in[15];
    const float* sch_pwb = (const float*)d_in[16];
    const float* scv_dw  = (const float*)d_in[17];
    const float* scv_dwb = (const float*)d_in[18];
    const float* scv_pw  = (const float*)d_in[19];
    const float* scv_pwb = (const float*)d_in[20];
    const float* convh_w = (const float*)d_in[21];
    const float* convh_b = (const float*)d_in[22];
    const float* dsc_dw  = (const float*)d_in[23];
    const float* dsc_dwb = (const float*)d_in[24];
    const float* dsc_pw  = (const float*)d_in[25];
    const float* dsc_pwb = (const float*)d_in[26];
    const float* ln_g    = (const float*)d_in[27];
    const float* ln_b    = (const float*)d_in[28];

    float* ws = (float*)d_ws;
    const size_t SZ = (size_t)Bn * Np * Cn;   // 1,048,576 elements
    float* xp   = ws;                 // pooled input BCHW; later p_norm
    float* xV   = ws + SZ;            // BNC fp32
    float* Op   = ws + 2 * SZ;        // attn partials (2 SZ); aliases gh/gv, dsc temp/out
    float* gh   = Op;
    float* gv   = Op + SZ;
    ushort_t* bws  = (ushort_t*)(ws + 4 * SZ);
    ushort_t* qb   = bws;             // bf16 BNC (pre-scaled SCALE2)
    ushort_t* kb_  = bws + SZ;        // bf16 BNC
    ushort_t* vb   = bws + 2 * SZ;    // bf16 BCHW (V^T)
    ushort_t* xKb  = bws + 3 * SZ;    // bf16 BNC
    ushort_t* xVtb = bws + 4 * SZ;    // bf16 BCHW (V^T)
    ushort_t* xQb  = bws + 5 * SZ;    // bf16 BNC (pre-scaled SCALE2)
    float* gap4k  = ws + 7 * SZ;                    // 4096 per-block partials
    float* Lpart  = gap4k + 4096;                   // NSPLIT*Bn*Np = 32768
    float* Wc1  = Lpart + (size_t)NSPLIT * Bn * Np; // 4096
    float* Wc2  = Wc1 + 4096;                       // 4096
    float* bcv  = Wc2 + 4096;                       // 64

    dim3 g64(64, Bn);
    dim3 ga((Np / 32) * NSPLIT, Bn);

    // avgpool + GAP partials + (merged) weight combine
    avgpool_kernel<<<4096 + 32, 256, 0, stream>>>(x, xp, gap4k,
                                                  convh_w, convh_b, sch_pw, sch_pwb,
                                                  scv_pw, scv_pwb, Wc1, Wc2, bcv);
    // q,k,v + x_V
    qkv_mfma<<<g64, 256, 0, stream>>>(xp, gap4k, Wq, bq, Wk, bk, Wv, bv, Wo, bo,
                                      qb, kb_, vb, xV, xVtb);
    // attention 1
    attn_mfma_kernel<<<ga, 128, 0, stream>>>(qb, kb_, vb, Op, Lpart);
    // x_K = linear(combine(attn1), Wl)
    wl_mfma<<<g64, 256, 0, stream>>>(Op, Lpart, Wl, bl, xKb);
    // strip convs (separate elementwise kernel — R7 staging fusion regressed)
    dwpair_kernel<<<4096, 256, 0, stream>>>(xp, sch_dw, sch_dwb, scv_dw, scv_dwb, gh, gv);
    // x_Q (combined weights, SCALE2 folded)
    hpg_mfma<<<g64, 256, 0, stream>>>(gh, gv, Wc1, Wc2, bcv, xQb);
    // attention 2
    attn_mfma_kernel<<<ga, 128, 0, stream>>>(xQb, xKb, xVtb, Op, Lpart);
    // prompt = linear(combine, Wp) + x_V ; LN ; -> BCHW (xp reused as p_norm)
    linln_mfma<<<g64, 256, 0, stream>>>(Op, Lpart, Wp, bp, xV, ln_g, ln_b, xp);
    // dsc
    dw3x3_gelu_kernel<<<4096, 256, 0, stream>>>(xp, dsc_dw, dsc_dwb, gh);
    dsc_mfma<<<g64, 256, 0, stream>>>(gh, dsc_pw, dsc_pwb, xp, gv);
    // bilinear x2
    upsample_kernel<<<16384, 256, 0, stream>>>(gv, (float*)d_out);
}

// Round 9
// 243.860 us; speedup vs baseline: 1.3642x; 1.1533x over previous
//
#include <hip/hip_runtime.h>
#include <math.h>

// Problem constants
#define Bn 4
#define Cn 64
#define Np 4096   // 64*64
#define NSPLIT 4
// SCALE * log2(e): folded into all Q pre-scales; attention uses exp2f (native v_exp_f32)
#define SCALE2 0.18033688011112042f

typedef unsigned short ushort_t;
typedef __attribute__((ext_vector_type(4))) float f32x4;
typedef __attribute__((ext_vector_type(8))) short bf16x8;
typedef __attribute__((ext_vector_type(4))) short bf16x4;

__device__ __forceinline__ float gelu_exact(float x) {
    return 0.5f * x * (1.0f + erff(x * 0.70710678118654752440f));
}
__device__ __forceinline__ ushort_t f2bf(float f) {       // RNE float->bf16
    unsigned int u = __float_as_uint(f);
    u += 0x7fffu + ((u >> 16) & 1u);
    return (ushort_t)(u >> 16);
}
__device__ __forceinline__ ushort_t f2bf_tr(float f) {    // truncating (1 VALU)
    return (ushort_t)(__float_as_uint(f) >> 16);
}
__device__ __forceinline__ float bf2f(ushort_t h) {
    return __uint_as_float(((unsigned int)h) << 16);
}
__device__ __forceinline__ void gload_lds16(const ushort_t* g, ushort_t* l) {
    __builtin_amdgcn_global_load_lds(
        (const __attribute__((address_space(1))) void*)g,
        (__attribute__((address_space(3))) void*)l, 16, 0, 0);
}
__device__ __forceinline__ bf16x8 cvt8(const float v[8]) {
    bf16x8 r;
    #pragma unroll
    for (int j = 0; j < 8; ++j) r[j] = (short)f2bf(v[j]);
    return r;
}
// Normal orientation: D[n][o]; acc C: row=n_sub, col=o.
__device__ __forceinline__ void gemm16(const bf16x8 af[2], const float* __restrict__ W,
                                       int l16, int quad, f32x4* acc) {
    #pragma unroll
    for (int cb = 0; cb < 4; ++cb) {
        #pragma unroll
        for (int ks = 0; ks < 2; ++ks) {
            const float* p = W + (cb * 16 + l16) * 64 + ks * 32 + quad * 8;
            float v[8];
            #pragma unroll
            for (int j = 0; j < 8; ++j) v[j] = p[j];
            acc[cb] = __builtin_amdgcn_mfma_f32_16x16x32_bf16(af[ks], cvt8(v), acc[cb], 0, 0, 0);
        }
    }
}
// Transposed orientation: D[o][n]; acc C: row=o_sub, col=n -> ushort4 channel-packed stores.
__device__ __forceinline__ void gemm16T(const bf16x8 af[2], const float* __restrict__ W,
                                        int l16, int quad, f32x4* acc) {
    #pragma unroll
    for (int cb = 0; cb < 4; ++cb) {
        #pragma unroll
        for (int ks = 0; ks < 2; ++ks) {
            const float* p = W + (cb * 16 + l16) * 64 + ks * 32 + quad * 8;
            float v[8];
            #pragma unroll
            for (int j = 0; j < 8; ++j) v[j] = p[j];
            acc[cb] = __builtin_amdgcn_mfma_f32_16x16x32_bf16(cvt8(v), af[ks], acc[cb], 0, 0, 0);
        }
    }
}
__device__ __forceinline__ void aload(const float* xs, int row, int quad, bf16x8 af[2]) {
    #pragma unroll
    for (int ks = 0; ks < 2; ++ks) {
        float v[8];
        #pragma unroll
        for (int j = 0; j < 8; ++j) v[j] = xs[(ks * 32 + quad * 8 + j) * 65 + row];
        af[ks] = cvt8(v);
    }
}
__device__ __forceinline__ void stage_bchw(const float* __restrict__ X, int b, int n0, int t,
                                           float* xs) {
    #pragma unroll
    for (int u = 0; u < 16; ++u) {
        int idx = t + u * 256;
        int c = idx >> 6, nl = idx & 63;
        xs[c * 65 + nl] = X[((size_t)(b * Cn + c)) * Np + n0 + nl];
    }
}
// combine NSPLIT bf16 attention partials * 1/l -> fp32 xs tile
__device__ __forceinline__ void stage_comb(const ushort_t* __restrict__ OpB, const float* linv,
                                           int b, int n0, int t, float* xs) {
    const size_t SS = (size_t)Bn * Np * Cn;
    #pragma unroll
    for (int u = 0; u < 16; ++u) {
        int idx = t + u * 256;
        int nl = idx >> 6, c = idx & 63;
        size_t gi = ((size_t)(b * Np + n0 + nl)) * Cn + c;
        float s = bf2f(OpB[gi]) + bf2f(OpB[SS + gi]) +
                  bf2f(OpB[2 * SS + gi]) + bf2f(OpB[3 * SS + gi]);
        xs[c * 65 + nl] = s * linv[nl];
    }
}
__device__ __forceinline__ void store_bnc_T(ushort_t* __restrict__ Y, int b, int n, int quad,
                                            const f32x4* acc, const float* __restrict__ bias,
                                            float mult) {
    #pragma unroll
    for (int cb = 0; cb < 4; ++cb) {
        int o0 = cb * 16 + quad * 4;
        ushort4 pk;
        pk.x = f2bf((acc[cb][0] + bias[o0 + 0]) * mult);
        pk.y = f2bf((acc[cb][1] + bias[o0 + 1]) * mult);
        pk.z = f2bf((acc[cb][2] + bias[o0 + 2]) * mult);
        pk.w = f2bf((acc[cb][3] + bias[o0 + 3]) * mult);
        *(ushort4*)(Y + ((size_t)(b * Np + n)) * Cn + o0) = pk;
    }
}
__device__ __forceinline__ void store_bchw_bf16(ushort_t* __restrict__ Y, int b, int nb, int l16,
                                                const f32x4* acc, const float* __restrict__ bias) {
    #pragma unroll
    for (int cb = 0; cb < 4; ++cb) {
        int col = cb * 16 + l16;
        float bb = bias[col];
        ushort4 pk;
        pk.x = f2bf(acc[cb][0] + bb); pk.y = f2bf(acc[cb][1] + bb);
        pk.z = f2bf(acc[cb][2] + bb); pk.w = f2bf(acc[cb][3] + bb);
        *(ushort4*)(Y + ((size_t)(b * Cn + col)) * Np + nb) = pk;
    }
}

// ---------------------------------------------------------------- avgpool 2x2 + GAP partials + wcomb
__global__ void avgpool_kernel(const float* __restrict__ x, float* __restrict__ xp,
                               float* __restrict__ gap4k,
                               const float* __restrict__ convh_w, const float* __restrict__ convh_b,
                               const float* __restrict__ sch_pw, const float* __restrict__ sch_pwb,
                               const float* __restrict__ scv_pw, const float* __restrict__ scv_pwb,
                               float* __restrict__ Wc1, float* __restrict__ Wc2,
                               float* __restrict__ bcv) {
    if (blockIdx.x < 4096) {
        int idx = blockIdx.x * 256 + threadIdx.x;
        int j  = idx & 63;
        int i  = (idx >> 6) & 63;
        int bc = idx >> 12;
        const float* p = x + ((size_t)bc * 128 + 2 * i) * 128 + 2 * j;
        float v = 0.25f * (p[0] + p[1] + p[128] + p[129]);
        xp[idx] = v;
        float s = v;
        #pragma unroll
        for (int off = 1; off < 64; off <<= 1) s += __shfl_xor(s, off, 64);
        __shared__ float sm[4];
        if ((threadIdx.x & 63) == 0) sm[threadIdx.x >> 6] = s;
        __syncthreads();
        if (threadIdx.x == 0) gap4k[blockIdx.x] = sm[0] + sm[1] + sm[2] + sm[3];
    } else {
        int g = (blockIdx.x - 4096) * 256 + threadIdx.x;   // 8192 threads
        int sel = g >> 12, idx = g & 4095;
        int o = idx >> 6, c = idx & 63;
        const float* pw = sel ? scv_pw : sch_pw;
        float acc = 0.f;
        #pragma unroll 8
        for (int m = 0; m < 64; ++m) acc += convh_w[o * 64 + m] * pw[m * 64 + c];
        (sel ? Wc2 : Wc1)[idx] = acc * SCALE2;
        if (g < 64) {
            float ab = convh_b[g];
            for (int m = 0; m < 64; ++m) ab += convh_w[g * 64 + m] * (sch_pwb[m] + scv_pwb[m]);
            bcv[g] = ab * SCALE2;
        }
    }
}

// ---------------------------------------------------------------- merged: QKV+Wo (x<64) | dwpair (x>=64)
__global__ __launch_bounds__(256) void qkv_dw_kernel(
    const float* __restrict__ xp, const float* __restrict__ gap4k,
    const float* __restrict__ Wq, const float* __restrict__ bq,
    const float* __restrict__ Wk, const float* __restrict__ bk,
    const float* __restrict__ Wv, const float* __restrict__ bv,
    const float* __restrict__ Wo, const float* __restrict__ bo,
    ushort_t* __restrict__ qb, ushort_t* __restrict__ kb, ushort_t* __restrict__ vb,
    float* __restrict__ xV, ushort_t* __restrict__ xVtb,
    const float* __restrict__ wv5, const float* __restrict__ bv5,
    const float* __restrict__ wh5, const float* __restrict__ bh5,
    ushort_t* __restrict__ gh, ushort_t* __restrict__ gv) {
    int b = blockIdx.y, t = threadIdx.x;
    if (blockIdx.x >= 64) {
        // ---- dwpair: 4 consecutive elems/thread, bf16 outputs
        int part = blockIdx.x - 64;                  // 0..255
        int e = part * 1024 + t * 4;                 // within-batch offset
        size_t base = (size_t)b * (Cn * Np) + e;
        int c = e >> 12, i = (e >> 6) & 63, j = e & 63;
        const float* p = xp + ((size_t)(b * Cn + c)) * Np;
        float accV[4], accH[4];
        #pragma unroll
        for (int k = 0; k < 4; ++k) { accV[k] = bv5[c]; accH[k] = bh5[c]; }
        #pragma unroll
        for (int d = 0; d < 5; ++d) {
            int ii = i + d - 2;
            if (ii >= 0 && ii < 64) {
                #pragma unroll
                for (int k = 0; k < 4; ++k) accV[k] += wv5[c * 5 + d] * p[ii * 64 + j + k];
            }
        }
        #pragma unroll
        for (int k = 0; k < 4; ++k) {
            #pragma unroll
            for (int d = 0; d < 5; ++d) {
                int jj = j + k + d - 2;
                if (jj >= 0 && jj < 64) accH[k] += wh5[c * 5 + d] * p[i * 64 + jj];
            }
        }
        ushort4 ph, pv_;
        ph.x = f2bf(gelu_exact(accV[0])); ph.y = f2bf(gelu_exact(accV[1]));
        ph.z = f2bf(gelu_exact(accV[2])); ph.w = f2bf(gelu_exact(accV[3]));
        pv_.x = f2bf(gelu_exact(accH[0])); pv_.y = f2bf(gelu_exact(accH[1]));
        pv_.z = f2bf(gelu_exact(accH[2])); pv_.w = f2bf(gelu_exact(accH[3]));
        *(ushort4*)(gh + base) = ph;
        *(ushort4*)(gv + base) = pv_;
        return;
    }
    // ---- QKV + Wo
    __shared__ float xs[64 * 65];
    __shared__ float gl[64];
    int n0 = blockIdx.x * 64;
    int wv_ = t >> 6, lane = t & 63, l16 = lane & 15, quad = lane >> 4;
    stage_bchw(xp, b, n0, t, xs);
    if (t < 64) {
        float s = 0.f;
        #pragma unroll
        for (int u = 0; u < 16; ++u) s += gap4k[(b * 64 + t) * 16 + u];
        gl[t] = s * (1.f / 4096.f);
    }
    __syncthreads();
    int row = wv_ * 16 + l16;
    int n   = n0 + wv_ * 16 + l16;
    int nb  = n0 + wv_ * 16 + quad * 4;
    bf16x8 ar[2], ag[2];
    #pragma unroll
    for (int ks = 0; ks < 2; ++ks) {
        float vr[8], vg[8];
        #pragma unroll
        for (int j = 0; j < 8; ++j) {
            int k = ks * 32 + quad * 8 + j;
            float xv = xs[k * 65 + row];
            vr[j] = xv; vg[j] = xv * gl[k];
        }
        ar[ks] = cvt8(vr); ag[ks] = cvt8(vg);
    }
    f32x4 acc[4];
    #pragma unroll
    for (int cb = 0; cb < 4; ++cb) acc[cb] = (f32x4){0.f, 0.f, 0.f, 0.f};
    gemm16T(ag, Wq, l16, quad, acc);
    store_bnc_T(qb, b, n, quad, acc, bq, SCALE2);
    #pragma unroll
    for (int cb = 0; cb < 4; ++cb) acc[cb] = (f32x4){0.f, 0.f, 0.f, 0.f};
    gemm16T(ag, Wk, l16, quad, acc);
    store_bnc_T(kb, b, n, quad, acc, bk, 1.f);
    #pragma unroll
    for (int cb = 0; cb < 4; ++cb) acc[cb] = (f32x4){0.f, 0.f, 0.f, 0.f};
    gemm16(ag, Wv, l16, quad, acc);
    store_bchw_bf16(vb, b, nb, l16, acc, bv);
    #pragma unroll
    for (int cb = 0; cb < 4; ++cb) acc[cb] = (f32x4){0.f, 0.f, 0.f, 0.f};
    gemm16(ar, Wo, l16, quad, acc);
    #pragma unroll
    for (int cb = 0; cb < 4; ++cb) {
        int col = cb * 16 + l16;
        float bb = bo[col];
        ushort4 pk;
        float y0 = acc[cb][0] + bb, y1 = acc[cb][1] + bb, y2 = acc[cb][2] + bb, y3 = acc[cb][3] + bb;
        xV[((size_t)(b * Np + nb + 0)) * Cn + col] = y0;
        xV[((size_t)(b * Np + nb + 1)) * Cn + col] = y1;
        xV[((size_t)(b * Np + nb + 2)) * Cn + col] = y2;
        xV[((size_t)(b * Np + nb + 3)) * Cn + col] = y3;
        pk.x = f2bf(y0); pk.y = f2bf(y1); pk.z = f2bf(y2); pk.w = f2bf(y3);
        *(ushort4*)(xVtb + ((size_t)(b * Cn + col)) * Np + nb) = pk;
    }
}

// ---------------------------------------------------------------- attention body (device)
// 256 threads / 64 q-rows / 4 waves share staged 64-kv tiles. NSPLIT=4 splits.
// S^T orientation (register P), PV via 16x16x16, double-buffered global_load_lds.
// Swizzle key(r) = (r ^ (r>>3)) & 7 at 16B-chunk granularity.
__device__ __forceinline__ void attn_body(
    int xblk, int b, const ushort_t* __restrict__ Qb, const ushort_t* __restrict__ Kb,
    const ushort_t* __restrict__ Vtb, ushort_t* __restrict__ OpB, float* __restrict__ Lpart,
    ushort_t* smem) {
    ushort_t* kt0 = smem;            // [2][4096]
    ushort_t* vt0 = smem + 8192;     // [2][4096]
    int split = xblk >> 6;           // 0..3
    int qt    = xblk & 63;
    int n0    = qt * 64;
    int t     = threadIdx.x;         // 0..255
    int wave  = t >> 6, lane = t & 63;
    int l16   = lane & 15, quad = lane >> 4;

    const ushort_t* qp = Qb + ((size_t)(b * Np) + n0 + wave * 16 + l16) * Cn + quad * 8;
    bf16x8 aq0 = *(const bf16x8*)(qp);
    bf16x8 aq1 = *(const bf16x8*)(qp + 32);

    f32x4 oa[4];
    float psum = 0.f;
    #pragma unroll
    for (int db = 0; db < 4; ++db) oa[db] = (f32x4){0.f, 0.f, 0.f, 0.f};

    int lrow = lane >> 3;
    int kvbase = split * (Np / NSPLIT);      // 1024 kv per split
    const ushort_t* Kg = Qb == nullptr ? nullptr : Kb + ((size_t)b * Np) * Cn;
    const ushort_t* Vg = Vtb + ((size_t)b * Cn) * Np;

    auto stage = [&](int buf, int k0) {
        int wh = wave & 1;
        if (wave < 2) {
            ushort_t* dst = kt0 + buf * 4096 + wh * 2048;
            #pragma unroll
            for (int u = 0; u < 4; ++u) {
                int r = wh * 32 + u * 8 + lrow;
                int jsw = ((lane & 7) ^ lrow ^ (wh * 4 + u)) & 7;
                gload_lds16(Kg + ((size_t)(k0 + r)) * Cn + jsw * 8, dst + u * 512);
            }
        } else {
            ushort_t* dst = vt0 + buf * 4096 + wh * 2048;
            #pragma unroll
            for (int u = 0; u < 4; ++u) {
                int d = wh * 32 + u * 8 + lrow;
                int jsw = ((lane & 7) ^ lrow ^ (wh * 4 + u)) & 7;
                gload_lds16(Vg + (size_t)d * Np + k0 + jsw * 8, dst + u * 512);
            }
        }
    };
    const int NT = (Np / NSPLIT) / 64;       // 16
    stage(0, kvbase);
    __syncthreads();

    for (int m = 0; m < NT; ++m) {
        int cur = m & 1;
        if (m + 1 < NT) stage(1 - cur, kvbase + (m + 1) * 64);
        const ushort_t* ktc = kt0 + cur * 4096;
        const ushort_t* vtc = vt0 + cur * 4096;

        // S^T = K Q : C row = kv_sub, col = query(l16)
        f32x4 sa[4];
        #pragma unroll
        for (int cb = 0; cb < 4; ++cb) sa[cb] = (f32x4){0.f, 0.f, 0.f, 0.f};
        #pragma unroll
        for (int cb = 0; cb < 4; ++cb) {
            int key = ((l16 & 7) ^ (cb * 2 + (l16 >> 3))) & 7;
            const ushort_t* krow = ktc + (cb * 16 + l16) * 64;
            bf16x8 bk0 = *(const bf16x8*)(krow + ((quad    ) ^ key) * 8);
            bf16x8 bk1 = *(const bf16x8*)(krow + ((quad + 4) ^ key) * 8);
            sa[cb] = __builtin_amdgcn_mfma_f32_16x16x32_bf16(bk0, aq0, sa[cb], 0, 0, 0);
            sa[cb] = __builtin_amdgcn_mfma_f32_16x16x32_bf16(bk1, aq1, sa[cb], 0, 0, 0);
        }
        // p = 2^s; truncating bf16 pack straight into PV B-fragments
        bf16x4 pb[4];
        #pragma unroll
        for (int cb = 0; cb < 4; ++cb) {
            float p0 = exp2f(sa[cb][0]), p1 = exp2f(sa[cb][1]);
            float p2 = exp2f(sa[cb][2]), p3 = exp2f(sa[cb][3]);
            psum += (p0 + p1) + (p2 + p3);
            bf16x4 pk;
            pk[0] = (short)f2bf_tr(p0); pk[1] = (short)f2bf_tr(p1);
            pk[2] = (short)f2bf_tr(p2); pk[3] = (short)f2bf_tr(p3);
            pb[cb] = pk;
        }
        // O^T += V^T P^T
        #pragma unroll
        for (int kc = 0; kc < 4; ++kc) {
            #pragma unroll
            for (int db = 0; db < 4; ++db) {
                int d = db * 16 + l16;
                int key = ((l16 & 7) ^ (db * 2 + (l16 >> 3))) & 7;
                int phys = (kc * 2 + (quad >> 1)) ^ key;
                const ushort_t* va = vtc + d * 64 + phys * 8 + (quad & 1) * 4;
                bf16x4 av = *(const bf16x4*)va;
                oa[db] = __builtin_amdgcn_mfma_f32_16x16x16bf16_1k(av, pb[kc], oa[db], 0, 0, 0);
            }
        }
        __syncthreads();
    }
    psum += __shfl_xor(psum, 16, 64);
    psum += __shfl_xor(psum, 32, 64);
    size_t obase = ((size_t)(split * Bn + b)) * Np;
    int n = n0 + wave * 16 + l16;
    if (quad == 0) Lpart[obase + n] = psum;
    #pragma unroll
    for (int db = 0; db < 4; ++db) {
        ushort4 pk;
        pk.x = f2bf(oa[db][0]); pk.y = f2bf(oa[db][1]);
        pk.z = f2bf(oa[db][2]); pk.w = f2bf(oa[db][3]);
        *(ushort4*)(OpB + (obase + n) * Cn + db * 16 + quad * 4) = pk;
    }
}

// hpg body: bf16 gh/gv staged [n][c] stride 72, combined 1x1 (SCALE2 folded) -> xQb
__device__ __forceinline__ void hpg_body(
    int tile, int b, const ushort_t* __restrict__ gh, const ushort_t* __restrict__ gv,
    const float* __restrict__ Wc1, const float* __restrict__ Wc2, const float* __restrict__ bcv,
    ushort_t* __restrict__ xQb, ushort_t* smem) {
    ushort_t* xs1 = smem;            // 64 x 72
    ushort_t* xs2 = smem + 4608;
    int n0 = tile * 64, t = threadIdx.x;
    int wv_ = t >> 6, lane = t & 63, l16 = lane & 15, quad = lane >> 4;
    #pragma unroll
    for (int u = 0; u < 4; ++u) {
        int lin = u * 256 + t;
        int c = lin >> 4, nl4 = (lin & 15) * 4;
        size_t gi = ((size_t)(b * Cn + c)) * Np + n0 + nl4;
        ushort4 g1 = *(const ushort4*)(gh + gi);
        ushort4 g2 = *(const ushort4*)(gv + gi);
        xs1[(nl4 + 0) * 72 + c] = g1.x; xs1[(nl4 + 1) * 72 + c] = g1.y;
        xs1[(nl4 + 2) * 72 + c] = g1.z; xs1[(nl4 + 3) * 72 + c] = g1.w;
        xs2[(nl4 + 0) * 72 + c] = g2.x; xs2[(nl4 + 1) * 72 + c] = g2.y;
        xs2[(nl4 + 2) * 72 + c] = g2.z; xs2[(nl4 + 3) * 72 + c] = g2.w;
    }
    __syncthreads();
    int row = wv_ * 16 + l16;
    bf16x8 a1[2], a2[2];
    #pragma unroll
    for (int ks = 0; ks < 2; ++ks) {
        a1[ks] = *(const bf16x8*)(xs1 + row * 72 + ks * 32 + quad * 8);
        a2[ks] = *(const bf16x8*)(xs2 + row * 72 + ks * 32 + quad * 8);
    }
    f32x4 acc[4];
    #pragma unroll
    for (int cb = 0; cb < 4; ++cb) acc[cb] = (f32x4){0.f, 0.f, 0.f, 0.f};
    gemm16T(a1, Wc1, l16, quad, acc);
    gemm16T(a2, Wc2, l16, quad, acc);
    store_bnc_T(xQb, b, n0 + wv_ * 16 + l16, quad, acc, bcv, 1.f);
}

// merged launch: x<256 -> attention ; x>=256 -> hpg tile (x-256)
__global__ __launch_bounds__(256) void attn_hpg_kernel(
    const ushort_t* __restrict__ Qb, const ushort_t* __restrict__ Kb,
    const ushort_t* __restrict__ Vtb, ushort_t* __restrict__ OpB, float* __restrict__ Lpart,
    const ushort_t* __restrict__ gh, const ushort_t* __restrict__ gv,
    const float* __restrict__ Wc1, const float* __restrict__ Wc2,
    const float* __restrict__ bcv, ushort_t* __restrict__ xQb) {
    __shared__ ushort_t smem[16384];   // attn: 2x(4096+4096); hpg: 2x4608
    int b = blockIdx.y;
    if (blockIdx.x < 256)
        attn_body(blockIdx.x, b, Qb, Kb, Vtb, OpB, Lpart, smem);
    else
        hpg_body(blockIdx.x - 256, b, gh, gv, Wc1, Wc2, bcv, xQb, smem);
}

// ---------------------------------------------------------------- combine(attn1)+Wl -> xKb
__global__ __launch_bounds__(256) void wl_mfma(
    const ushort_t* __restrict__ OpB, const float* __restrict__ Lp,
    const float* __restrict__ Wl, const float* __restrict__ bl, ushort_t* __restrict__ xKb) {
    __shared__ float xs[64 * 65];
    __shared__ float linv[64];
    int b = blockIdx.y, n0 = blockIdx.x * 64, t = threadIdx.x;
    int wv_ = t >> 6, lane = t & 63, l16 = lane & 15, quad = lane >> 4;
    if (t < 64) {
        size_t li = (size_t)b * Np + n0 + t;
        const size_t LS = (size_t)Bn * Np;
        linv[t] = 1.f / (Lp[li] + Lp[LS + li] + Lp[2 * LS + li] + Lp[3 * LS + li]);
    }
    __syncthreads();
    stage_comb(OpB, linv, b, n0, t, xs);
    __syncthreads();
    bf16x8 af[2];
    aload(xs, wv_ * 16 + l16, quad, af);
    f32x4 acc[4];
    #pragma unroll
    for (int cb = 0; cb < 4; ++cb) acc[cb] = (f32x4){0.f, 0.f, 0.f, 0.f};
    gemm16T(af, Wl, l16, quad, acc);
    store_bnc_T(xKb, b, n0 + wv_ * 16 + l16, quad, acc, bl, 1.f);
}

// ---------------------------------------------------------------- combine(attn2)+Wp+res+LayerNorm -> BCHW
__global__ __launch_bounds__(256) void linln_mfma(
    const ushort_t* __restrict__ OpB, const float* __restrict__ Lp,
    const float* __restrict__ Wp, const float* __restrict__ bp,
    const float* __restrict__ xV, const float* __restrict__ g, const float* __restrict__ beta,
    float* __restrict__ out) {
    __shared__ float xs[64 * 65];
    __shared__ float linv[64];
    int b = blockIdx.y, n0 = blockIdx.x * 64, t = threadIdx.x;
    int wv_ = t >> 6, lane = t & 63, l16 = lane & 15, quad = lane >> 4;
    if (t < 64) {
        size_t li = (size_t)b * Np + n0 + t;
        const size_t LS = (size_t)Bn * Np;
        linv[t] = 1.f / (Lp[li] + Lp[LS + li] + Lp[2 * LS + li] + Lp[3 * LS + li]);
    }
    __syncthreads();
    stage_comb(OpB, linv, b, n0, t, xs);
    __syncthreads();
    bf16x8 af[2];
    aload(xs, wv_ * 16 + l16, quad, af);
    f32x4 acc[4];
    #pragma unroll
    for (int cb = 0; cb < 4; ++cb) acc[cb] = (f32x4){0.f, 0.f, 0.f, 0.f};
    gemm16(af, Wp, l16, quad, acc);
    int nb = n0 + wv_ * 16 + quad * 4;
    float vals[4][4], gc[4], bec[4];
    #pragma unroll
    for (int cb = 0; cb < 4; ++cb) {
        int col = cb * 16 + l16;
        float bb = bp[col];
        gc[cb] = g[col]; bec[cb] = beta[col];
        #pragma unroll
        for (int r = 0; r < 4; ++r)
            vals[cb][r] = acc[cb][r] + bb + xV[((size_t)(b * Np + nb + r)) * Cn + col];
    }
    f32x4 yn[4];
    #pragma unroll
    for (int r = 0; r < 4; ++r) {
        float s = 0.f, s2 = 0.f;
        #pragma unroll
        for (int cb = 0; cb < 4; ++cb) { s += vals[cb][r]; s2 += vals[cb][r] * vals[cb][r]; }
        #pragma unroll
        for (int off = 1; off < 16; off <<= 1) {
            s  += __shfl_xor(s, off, 64);
            s2 += __shfl_xor(s2, off, 64);
        }
        float mu  = s * (1.f / 64.f);
        float var = s2 * (1.f / 64.f) - mu * mu;
        float ivs = rsqrtf(var + 1e-5f);
        #pragma unroll
        for (int cb = 0; cb < 4; ++cb)
            yn[cb][r] = (vals[cb][r] - mu) * ivs * gc[cb] + bec[cb];
    }
    #pragma unroll
    for (int cb = 0; cb < 4; ++cb)
        *(f32x4*)(out + ((size_t)(b * Cn + cb * 16 + l16)) * Np + nb) = yn[cb];
}

// ---------------------------------------------------------------- dw3x3 + GELU (elementwise)
__global__ void dw3x3_gelu_kernel(const float* __restrict__ xin, const float* __restrict__ w,
                                  const float* __restrict__ bias, float* __restrict__ out) {
    int idx = blockIdx.x * 256 + threadIdx.x;
    int j = idx & 63, i = (idx >> 6) & 63, bc = idx >> 12, c = bc & 63;
    const float* p = xin + (size_t)bc * Np;
    float acc = bias[c];
    #pragma unroll
    for (int dy = 0; dy < 3; ++dy) {
        int ii = i + dy - 1;
        if (ii < 0 || ii >= 64) continue;
        #pragma unroll
        for (int dx = 0; dx < 3; ++dx) {
            int jj = j + dx - 1;
            if (jj < 0 || jj >= 64) continue;
            acc += w[c * 9 + dy * 3 + dx] * p[ii * 64 + jj];
        }
    }
    out[idx] = gelu_exact(acc);
}

// ---------------------------------------------------------------- dsc 1x1 + residual -> BCHW
__global__ __launch_bounds__(256) void dsc_mfma(
    const float* __restrict__ X, const float* __restrict__ W, const float* __restrict__ bias,
    const float* __restrict__ res, float* __restrict__ out) {
    __shared__ float xs[64 * 65];
    int b = blockIdx.y, n0 = blockIdx.x * 64, t = threadIdx.x;
    int wv_ = t >> 6, lane = t & 63, l16 = lane & 15, quad = lane >> 4;
    stage_bchw(X, b, n0, t, xs);
    __syncthreads();
    bf16x8 af[2];
    aload(xs, wv_ * 16 + l16, quad, af);
    f32x4 acc[4];
    #pragma unroll
    for (int cb = 0; cb < 4; ++cb) acc[cb] = (f32x4){0.f, 0.f, 0.f, 0.f};
    gemm16(af, W, l16, quad, acc);
    int nb = n0 + wv_ * 16 + quad * 4;
    #pragma unroll
    for (int cb = 0; cb < 4; ++cb) {
        int col = cb * 16 + l16;
        float bb = bias[col];
        size_t oi = ((size_t)(b * Cn + col)) * Np + nb;
        f32x4 rv = *(const f32x4*)(res + oi);
        f32x4 v4;
        #pragma unroll
        for (int r = 0; r < 4; ++r) v4[r] = acc[cb][r] + bb + rv[r];
        *(f32x4*)(out + oi) = v4;
    }
}

// ---------------------------------------------------------------- bilinear x2 upsample
__global__ void upsample_kernel(const float* __restrict__ in, float* __restrict__ out) {
    int idx = blockIdx.x * 256 + threadIdx.x;
    int x  = idx & 127;
    int y  = (idx >> 7) & 127;
    int bc = idx >> 14;
    float sy = y * (63.f / 127.f);
    float sx = x * (63.f / 127.f);
    int y0 = (int)sy, x0 = (int)sx;
    float fy = sy - y0, fx = sx - x0;
    int y1 = min(y0 + 1, 63), x1 = min(x0 + 1, 63);
    const float* p = in + (size_t)bc * Np;
    float v00 = p[y0 * 64 + x0], v01 = p[y0 * 64 + x1];
    float v10 = p[y1 * 64 + x0], v11 = p[y1 * 64 + x1];
    out[idx] = (v00 * (1.f - fx) + v01 * fx) * (1.f - fy) +
               (v10 * (1.f - fx) + v11 * fx) * fy;
}

// ----------------------------------------------------------------
extern "C" void kernel_launch(void* const* d_in, const int* in_sizes, int n_in,
                              void* d_out, int out_size, void* d_ws, size_t ws_size,
                              hipStream_t stream) {
    const float* x       = (const float*)d_in[0];
    const float* Wq      = (const float*)d_in[1];
    const float* bq      = (const float*)d_in[2];
    const float* Wk      = (const float*)d_in[3];
    const float* bk      = (const float*)d_in[4];
    const float* Wv      = (const float*)d_in[5];
    const float* bv      = (const float*)d_in[6];
    const float* Wl      = (const float*)d_in[7];
    const float* bl      = (const float*)d_in[8];
    const float* Wo      = (const float*)d_in[9];
    const float* bo      = (const float*)d_in[10];
    const float* Wp      = (const float*)d_in[11];
    const float* bp      = (const float*)d_in[12];
    const float* sch_dw  = (const float*)d_in[13];
    const float* sch_dwb = (const float*)d_in[14];
    const float* sch_pw  = (const float*)d_in[15];
    const float* sch_pwb = (const float*)d_in[16];
    const float* scv_dw  = (const float*)d_in[17];
    const float* scv_dwb = (const float*)d_in[18];
    const float* scv_pw  = (const float*)d_in[19];
    const float* scv_pwb = (const float*)d_in[20];
    const float* convh_w = (const float*)d_in[21];
    const float* convh_b = (const float*)d_in[22];
    const float* dsc_dw  = (const float*)d_in[23];
    const float* dsc_dwb = (const float*)d_in[24];
    const float* dsc_pw  = (const float*)d_in[25];
    const float* dsc_pwb = (const float*)d_in[26];
    const float* ln_g    = (const float*)d_in[27];
    const float* ln_b    = (const float*)d_in[28];

    float* ws = (float*)d_ws;
    const size_t SZ = (size_t)Bn * Np * Cn;   // 1,048,576 elements
    float* xp   = ws;                          // pooled BCHW; later p_norm
    float* xV   = ws + SZ;                     // BNC fp32; later dw3x3 out
    ushort_t* ghb = (ushort_t*)(ws + 2 * SZ);  // bf16 gh/gv (floats 2SZ..3SZ)
    ushort_t* gh  = ghb;
    ushort_t* gv  = ghb + SZ;
    float* f2   = ws + 2 * SZ;                 // dsc out (reuses gh/gv region later)
    ushort_t* bws  = (ushort_t*)(ws + 3 * SZ); // floats 3SZ..6SZ
    ushort_t* qb   = bws;
    ushort_t* kb_  = bws + SZ;
    ushort_t* vb   = bws + 2 * SZ;             // bf16 BCHW (V^T)
    ushort_t* xKb  = bws + 3 * SZ;
    ushort_t* xVtb = bws + 4 * SZ;             // bf16 BCHW (V^T)
    ushort_t* xQb  = bws + 5 * SZ;
    ushort_t* OpB  = (ushort_t*)(ws + 6 * SZ); // bf16 partials, 4 x SZ ushorts (floats 6SZ..8SZ)
    float* gap4k  = ws + 8 * SZ;                        // 4096
    float* Lpart  = gap4k + 4096;                       // NSPLIT*Bn*Np = 65536
    float* Wc1  = Lpart + (size_t)NSPLIT * Bn * Np;     // 4096
    float* Wc2  = Wc1 + 4096;                           // 4096
    float* bcv  = Wc2 + 4096;                           // 64

    dim3 g64(64, Bn);

    // 1) avgpool + GAP partials + weight combine
    avgpool_kernel<<<4096 + 32, 256, 0, stream>>>(x, xp, gap4k,
                                                  convh_w, convh_b, sch_pw, sch_pwb,
                                                  scv_pw, scv_pwb, Wc1, Wc2, bcv);
    // 2) qkv(+Wo) merged with dwpair (bf16 gh/gv)
    qkv_dw_kernel<<<dim3(64 + 256, Bn), 256, 0, stream>>>(
        xp, gap4k, Wq, bq, Wk, bk, Wv, bv, Wo, bo,
        qb, kb_, vb, xV, xVtb, sch_dw, sch_dwb, scv_dw, scv_dwb, gh, gv);
    // 3) attention 1 merged with hpg (x_Q)
    attn_hpg_kernel<<<dim3(256 + 64, Bn), 256, 0, stream>>>(
        qb, kb_, vb, OpB, Lpart, gh, gv, Wc1, Wc2, bcv, xQb);
    // 4) x_K = linear(combine(attn1), Wl)
    wl_mfma<<<g64, 256, 0, stream>>>(OpB, Lpart, Wl, bl, xKb);
    // 5) attention 2 (same kernel, attn blocks only)
    attn_hpg_kernel<<<dim3(256, Bn), 256, 0, stream>>>(
        xQb, xKb, xVtb, OpB, Lpart, gh, gv, Wc1, Wc2, bcv, xQb);
    // 6) prompt = linear(combine, Wp) + x_V ; LN ; -> BCHW (xp reused as p_norm)
    linln_mfma<<<g64, 256, 0, stream>>>(OpB, Lpart, Wp, bp, xV, ln_g, ln_b, xp);
    // 7) dsc depthwise (xV reused as conv out)
    dw3x3_gelu_kernel<<<4096, 256, 0, stream>>>(xp, dsc_dw, dsc_dwb, xV);
    // 8) dsc 1x1 + residual
    dsc_mfma<<<g64, 256, 0, stream>>>(xV, dsc_pw, dsc_pwb, xp, f2);
    // 9) bilinear x2
    upsample_kernel<<<16384, 256, 0, stream>>>(f2, (float*)d_out);
}